// Round 1
// baseline (14229.782 us; speedup 1.0000x reference)
//
#include <hip/hip_runtime.h>
#include <hip/hip_bf16.h>
#include <math.h>

// ---------------- model constants ----------------
#define BATCH 64
#define CDIM 384
#define NHEADS 6
#define HD 64
#define MLPD 1536
#define NLAYERS 12
#define NPATCH 196
#define NTOK0 197
#define NCLS 100

// ---------------- wave helpers ----------------
__device__ inline float wave_sum(float v) {
  #pragma unroll
  for (int o = 32; o > 0; o >>= 1) v += __shfl_xor(v, o);
  return v;
}
__device__ inline float wave_max(float v) {
  #pragma unroll
  for (int o = 32; o > 0; o >>= 1) v = fmaxf(v, __shfl_xor(v, o));
  return v;
}

// ---------------- im2col: x[B,3,224,224] -> P[B*196, 768] ----------------
__global__ __launch_bounds__(256) void im2col_kernel(const float* __restrict__ x, float* __restrict__ P) {
  int i = blockIdx.x * 256 + threadIdx.x;
  const int total = BATCH * NPATCH * 768;
  if (i >= total) return;
  int k = i % 768;          // c*256 + py*16 + px
  int row = i / 768;        // b*196 + p
  int c = k >> 8;
  int r = k & 255;
  int py = r >> 4, px = r & 15;
  int b = row / NPATCH;
  int p = row % NPATCH;
  int gy = p / 14, gx = p % 14;
  P[i] = x[(((size_t)b * 3 + c) * 224 + gy * 16 + py) * 224 + gx * 16 + px];
}

// ---------------- assemble: h[b,0]=cls+pos0; h[b,1+p]=patchout+pos ----------------
__global__ __launch_bounds__(256) void assemble_kernel(const float* __restrict__ patchout,
                                                       const float* __restrict__ cls_tok,
                                                       const float* __restrict__ pos,
                                                       float* __restrict__ h) {
  int i = blockIdx.x * 256 + threadIdx.x;
  const int total = BATCH * NTOK0 * CDIM;
  if (i >= total) return;
  int c = i % CDIM;
  int n = (i / CDIM) % NTOK0;
  int b = i / (CDIM * NTOK0);
  float v = (n == 0) ? cls_tok[c] : patchout[((size_t)b * NPATCH + (n - 1)) * CDIM + c];
  h[i] = v + pos[n * CDIM + c];
}

// ---------------- generic tiled f32 GEMM: out = act(A@W + bias) + res ----------------
// A: [M,K] row-major, W: [K,N] row-major, bias: [N], res: [M,N] or null.
// act: 0=none, 1=exact gelu
__global__ __launch_bounds__(256) void gemm_f32(const float* __restrict__ A, const float* __restrict__ W,
                                                const float* __restrict__ bias, const float* __restrict__ res,
                                                float* __restrict__ out,
                                                int M, int N, int K, int act) {
  __shared__ __align__(16) float As[16][64];
  __shared__ __align__(16) float Ws[16][64];
  const int tid = threadIdx.x;
  const int tx = tid & 15, ty = tid >> 4;
  const int bm = blockIdx.y * 64, bn = blockIdx.x * 64;
  float acc[4][4] = {};

  const int ma = tid >> 2;            // 0..63  (A-tile row)
  const int ka = (tid & 3) << 2;      // 0,4,8,12
  const int kw = ty;                  // 0..15  (W-tile k)
  const int nw = tx << 2;             // 0..60

  for (int k0 = 0; k0 < K; k0 += 16) {
    // A tile -> As[k][m] (transposed)
    {
      float4 a4 = make_float4(0.f, 0.f, 0.f, 0.f);
      if (bm + ma < M) a4 = *reinterpret_cast<const float4*>(&A[(size_t)(bm + ma) * K + k0 + ka]);
      As[ka + 0][ma] = a4.x; As[ka + 1][ma] = a4.y; As[ka + 2][ma] = a4.z; As[ka + 3][ma] = a4.w;
    }
    // W tile -> Ws[k][n]
    {
      const int gn = bn + nw;
      const float* wp = &W[(size_t)(k0 + kw) * N + gn];
      if (gn + 3 < N) {
        float4 w4 = *reinterpret_cast<const float4*>(wp);
        Ws[kw][nw + 0] = w4.x; Ws[kw][nw + 1] = w4.y; Ws[kw][nw + 2] = w4.z; Ws[kw][nw + 3] = w4.w;
      } else {
        #pragma unroll
        for (int j = 0; j < 4; ++j) Ws[kw][nw + j] = (gn + j < N) ? wp[j] : 0.f;
      }
    }
    __syncthreads();
    #pragma unroll
    for (int kk = 0; kk < 16; ++kk) {
      float4 a = *reinterpret_cast<const float4*>(&As[kk][ty << 2]);
      float4 w = *reinterpret_cast<const float4*>(&Ws[kk][tx << 2]);
      float av[4] = {a.x, a.y, a.z, a.w};
      float wv[4] = {w.x, w.y, w.z, w.w};
      #pragma unroll
      for (int i = 0; i < 4; ++i)
        #pragma unroll
        for (int j = 0; j < 4; ++j)
          acc[i][j] = fmaf(av[i], wv[j], acc[i][j]);
    }
    __syncthreads();
  }

  #pragma unroll
  for (int i = 0; i < 4; ++i) {
    int r = bm + (ty << 2) + i;
    if (r >= M) continue;
    #pragma unroll
    for (int j = 0; j < 4; ++j) {
      int cidx = bn + (tx << 2) + j;
      if (cidx >= N) continue;
      float v = acc[i][j] + bias[cidx];
      if (act == 1) v = 0.5f * v * (1.0f + erff(v * 0.70710678118654752f));
      if (res) v += res[(size_t)r * N + cidx];
      out[(size_t)r * N + cidx] = v;
    }
  }
}

// ---------------- layernorm (one wave per row, C=384) ----------------
__global__ __launch_bounds__(64) void ln_kernel(const float* __restrict__ in, float* __restrict__ out,
                                                const float* __restrict__ g, const float* __restrict__ bb,
                                                int rows, size_t in_stride, size_t out_stride) {
  int r = blockIdx.x;
  if (r >= rows) return;
  const float* xr = in + (size_t)r * in_stride;
  float* orow = out + (size_t)r * out_stride;
  int t = threadIdx.x;
  float v[6];
  float s = 0.f;
  #pragma unroll
  for (int i = 0; i < 6; ++i) { v[i] = xr[i * 64 + t]; s += v[i]; }
  s = wave_sum(s);
  float mean = s * (1.0f / CDIM);
  float q = 0.f;
  #pragma unroll
  for (int i = 0; i < 6; ++i) { float d = v[i] - mean; q += d * d; }
  q = wave_sum(q);
  float rstd = rsqrtf(q * (1.0f / CDIM) + 1e-6f);
  #pragma unroll
  for (int i = 0; i < 6; ++i) {
    int c = i * 64 + t;
    orow[c] = (v[i] - mean) * rstd * g[c] + bb[c];
  }
}

// ---------------- attention: one wave per (q-row, head, batch) ----------------
// qkv: [B, N, 3C] with q at col h*64, k at 384+h*64, v at 768+h*64
// out: [B, N, C] (head-concat layout). cls_attn: [B, H, N-1] softmax probs of row 0.
__global__ __launch_bounds__(64) void attn_kernel(const float* __restrict__ qkv, float* __restrict__ out,
                                                  float* __restrict__ cls_attn, int N) {
  const int n = blockIdx.x, h = blockIdx.y, b = blockIdx.z;
  const int t = threadIdx.x;
  __shared__ __align__(16) float sm_q[64];
  __shared__ float sm_s[224];

  const float* qrow = qkv + ((size_t)(b * N + n)) * (3 * CDIM) + h * HD;
  sm_q[t] = qrow[t];
  __syncthreads();

  const float4* q4 = reinterpret_cast<const float4*>(sm_q);
  for (int m = t; m < N; m += 64) {
    const float4* k4 = reinterpret_cast<const float4*>(qkv + ((size_t)(b * N + m)) * (3 * CDIM) + CDIM + h * HD);
    float acc = 0.f;
    #pragma unroll
    for (int d = 0; d < 16; ++d) {
      float4 kk = k4[d];
      float4 qq = q4[d];
      acc += qq.x * kk.x + qq.y * kk.y + qq.z * kk.z + qq.w * kk.w;
    }
    sm_s[m] = acc * 0.125f;  // HD^-0.5
  }
  __syncthreads();

  float mx = -INFINITY;
  for (int m = t; m < N; m += 64) mx = fmaxf(mx, sm_s[m]);
  mx = wave_max(mx);
  float sum = 0.f;
  for (int m = t; m < N; m += 64) {
    float e = expf(sm_s[m] - mx);
    sm_s[m] = e;
    sum += e;
  }
  sum = wave_sum(sum);
  float inv = 1.0f / sum;
  __syncthreads();

  // PV: thread t owns output dim d=t
  float acc = 0.f;
  const float* vbase = qkv + (size_t)b * N * (3 * CDIM) + 2 * CDIM + h * HD + t;
  for (int m = 0; m < N; ++m) {
    acc += sm_s[m] * vbase[(size_t)m * (3 * CDIM)];
  }
  out[((size_t)(b * N + n)) * CDIM + h * HD + t] = acc * inv;

  if (n == 0) {
    for (int m = t; m < N; m += 64)
      if (m >= 1) cls_attn[((size_t)b * NHEADS + h) * (N - 1) + (m - 1)] = sm_s[m] * inv;
  }
}

// ---------------- CLS score = mean over heads ----------------
__global__ __launch_bounds__(256) void clsscore_kernel(const float* __restrict__ cls_attn,
                                                       float* __restrict__ scores, int Nm1) {
  int i = blockIdx.x * 256 + threadIdx.x;
  if (i >= BATCH * Nm1) return;
  int b = i / Nm1, j = i % Nm1;
  float s = 0.f;
  #pragma unroll
  for (int h = 0; h < NHEADS; ++h) s += cls_attn[((size_t)b * NHEADS + h) * Nm1 + j];
  scores[i] = s * (1.0f / NHEADS);
}

// ---------------- iterative top-k (descending, ties -> smaller index) ----------------
__global__ __launch_bounds__(256) void topk_kernel(const float* __restrict__ scores, int* __restrict__ idx,
                                                   int Nm1, int Kkeep) {
  int b = blockIdx.x;
  int t = threadIdx.x;
  __shared__ float s_sc[224];
  __shared__ float rv[256];
  __shared__ int ri[256];
  if (t < Nm1) s_sc[t] = scores[b * Nm1 + t];
  __syncthreads();
  for (int k = 0; k < Kkeep; ++k) {
    rv[t] = (t < Nm1) ? s_sc[t] : -INFINITY;
    ri[t] = t;
    __syncthreads();
    for (int s = 128; s > 0; s >>= 1) {
      if (t < s) {
        float ov = rv[t + s]; int oi = ri[t + s];
        if (ov > rv[t] || (ov == rv[t] && oi < ri[t])) { rv[t] = ov; ri[t] = oi; }
      }
      __syncthreads();
    }
    if (t == 0) {
      idx[b * Kkeep + k] = ri[0];
      s_sc[ri[0]] = -INFINITY;
    }
    __syncthreads();
  }
}

// ---------------- gather pruned tokens ----------------
__global__ __launch_bounds__(256) void gather_kernel(const float* __restrict__ h, const int* __restrict__ idx,
                                                     float* __restrict__ outb, int N, int Kkeep) {
  size_t total = (size_t)BATCH * (1 + Kkeep) * CDIM;
  size_t i = (size_t)blockIdx.x * 256 + threadIdx.x;
  if (i >= total) return;
  int c = (int)(i % CDIM);
  size_t r = i / CDIM;
  int n = (int)(r % (1 + Kkeep));
  int b = (int)(r / (1 + Kkeep));
  int src = (n == 0) ? 0 : 1 + idx[b * Kkeep + (n - 1)];
  outb[i] = h[((size_t)b * N + src) * CDIM + c];
}

// ---------------- host launch ----------------
extern "C" void kernel_launch(void* const* d_in, const int* in_sizes, int n_in,
                              void* d_out, int out_size, void* d_ws, size_t ws_size,
                              hipStream_t stream) {
  const float* x        = (const float*)d_in[0];
  const float* patch_w  = (const float*)d_in[1];
  const float* patch_b  = (const float*)d_in[2];
  const float* cls_tok  = (const float*)d_in[3];
  const float* pos      = (const float*)d_in[4];
  const float* ln1_g    = (const float*)d_in[5];
  const float* ln1_b    = (const float*)d_in[6];
  const float* qkv_w    = (const float*)d_in[7];
  const float* qkv_b    = (const float*)d_in[8];
  const float* proj_w   = (const float*)d_in[9];
  const float* proj_b   = (const float*)d_in[10];
  const float* ln2_g    = (const float*)d_in[11];
  const float* ln2_b    = (const float*)d_in[12];
  const float* fc1_w    = (const float*)d_in[13];
  const float* fc1_b    = (const float*)d_in[14];
  const float* fc2_w    = (const float*)d_in[15];
  const float* fc2_b    = (const float*)d_in[16];
  const float* norm_g   = (const float*)d_in[17];
  const float* norm_b   = (const float*)d_in[18];
  const float* head_w   = (const float*)d_in[19];
  const float* head_b   = (const float*)d_in[20];
  float* out = (float*)d_out;

  float* ws = (float*)d_ws;
  // region layout (floats)
  float* h    = ws;                       // 4,841,472  [B,197,C] max
  float* lnb  = ws + 4841472;             // 4,841,472  LN out / attn out
  float* big  = ws + 9682944;             // 19,365,888 qkv / hidden / im2col / patchout / gather tmp
  float* cls_attn = ws + 29048832;        // 75,264
  float* scores   = ws + 29124096;        // 12,544
  int*   idxbuf   = (int*)(ws + 29136640);// 11,264 ints
  float* cls0     = ws + 29147904;        // 24,576

  // ---- patch embed ----
  {
    int total = BATCH * NPATCH * 768;
    im2col_kernel<<<(total + 255) / 256, 256, 0, stream>>>(x, big);
    dim3 g(CDIM / 64, (BATCH * NPATCH) / 64);
    gemm_f32<<<g, 256, 0, stream>>>(big, patch_w, patch_b, nullptr, big + 9633792,
                                    BATCH * NPATCH, CDIM, 768, 0);
    int tot2 = BATCH * NTOK0 * CDIM;
    assemble_kernel<<<(tot2 + 255) / 256, 256, 0, stream>>>(big + 9633792, cls_tok, pos, h);
  }

  int ncur = NTOK0;
  for (int i = 0; i < NLAYERS; ++i) {
    int M = BATCH * ncur;
    // LN1
    ln_kernel<<<M, 64, 0, stream>>>(h, lnb, ln1_g + i * CDIM, ln1_b + i * CDIM, M, CDIM, CDIM);
    // QKV
    {
      dim3 g((3 * CDIM) / 64, ncur);
      gemm_f32<<<g, 256, 0, stream>>>(lnb, qkv_w + (size_t)i * CDIM * 3 * CDIM,
                                      qkv_b + i * 3 * CDIM, nullptr, big, M, 3 * CDIM, CDIM, 0);
    }
    // attention (writes lnb as attn-out; also CLS probs)
    {
      dim3 g(ncur, NHEADS, BATCH);
      attn_kernel<<<g, 64, 0, stream>>>(big, lnb, cls_attn, ncur);
    }
    // proj + residual (in place on h)
    {
      dim3 g(CDIM / 64, ncur);
      gemm_f32<<<g, 256, 0, stream>>>(lnb, proj_w + (size_t)i * CDIM * CDIM,
                                      proj_b + i * CDIM, h, h, M, CDIM, CDIM, 0);
    }
    // prune
    if (i == 2 || i == 4 || i == 6) {
      int keep = (i == 2) ? 176 : (i == 4) ? 149 : 119;
      int Nm1 = ncur - 1;
      int tot = BATCH * Nm1;
      clsscore_kernel<<<(tot + 255) / 256, 256, 0, stream>>>(cls_attn, scores, Nm1);
      topk_kernel<<<BATCH, 256, 0, stream>>>(scores, idxbuf, Nm1, keep);
      int newN = 1 + keep;
      size_t gtot = (size_t)BATCH * newN * CDIM;
      gather_kernel<<<(int)((gtot + 255) / 256), 256, 0, stream>>>(h, idxbuf, big, ncur, keep);
      hipMemcpyAsync(h, big, gtot * sizeof(float), hipMemcpyDeviceToDevice, stream);
      ncur = newN;
      M = BATCH * ncur;
    }
    // LN2
    ln_kernel<<<M, 64, 0, stream>>>(h, lnb, ln2_g + i * CDIM, ln2_b + i * CDIM, M, CDIM, CDIM);
    // FC1 + gelu
    {
      dim3 g(MLPD / 64, ncur);
      gemm_f32<<<g, 256, 0, stream>>>(lnb, fc1_w + (size_t)i * CDIM * MLPD,
                                      fc1_b + i * MLPD, nullptr, big, M, MLPD, CDIM, 1);
    }
    // FC2 + residual (in place on h)
    {
      dim3 g(CDIM / 64, ncur);
      gemm_f32<<<g, 256, 0, stream>>>(big, fc2_w + (size_t)i * MLPD * CDIM,
                                      fc2_b + i * CDIM, h, h, M, CDIM, MLPD, 0);
    }
  }

  // final LN of CLS rows only, then head
  ln_kernel<<<BATCH, 64, 0, stream>>>(h, cls0, norm_g, norm_b, BATCH, (size_t)ncur * CDIM, CDIM);
  {
    dim3 g((NCLS + 63) / 64, 1);
    gemm_f32<<<g, 256, 0, stream>>>(cls0, head_w, head_b, nullptr, out, BATCH, NCLS, CDIM, 0);
  }
}

// Round 2
// 6544.798 us; speedup vs baseline: 2.1742x; 2.1742x over previous
//
#include <hip/hip_runtime.h>
#include <hip/hip_bf16.h>
#include <math.h>

// ---------------- model constants ----------------
#define BATCH 64
#define CDIM 384
#define NHEADS 6
#define HD 64
#define MLPD 1536
#define NLAYERS 12
#define NPATCH 196
#define NTOK0 197
#define NCLS 100

typedef unsigned short ushortT;
typedef __attribute__((ext_vector_type(8))) short short8v;
typedef __attribute__((ext_vector_type(4))) float float4v;

// ---------------- bf16 helpers ----------------
__device__ inline ushortT f2b(float f) {
  union { float f; unsigned u; } x; x.f = f;
  unsigned r = x.u + 0x7fffu + ((x.u >> 16) & 1u);
  return (ushortT)(r >> 16);
}
__device__ inline float b2f(ushortT u) {
  union { unsigned u; float f; } x; x.u = ((unsigned)u) << 16;
  return x.f;
}
__device__ inline float bflo(unsigned v) { union { unsigned u; float f; } x; x.u = v << 16; return x.f; }
__device__ inline float bfhi(unsigned v) { union { unsigned u; float f; } x; x.u = v & 0xffff0000u; return x.f; }

// ---------------- wave helpers ----------------
__device__ inline float wave_sum(float v) {
  #pragma unroll
  for (int o = 32; o > 0; o >>= 1) v += __shfl_xor(v, o);
  return v;
}
__device__ inline float wave_max(float v) {
  #pragma unroll
  for (int o = 32; o > 0; o >>= 1) v = fmaxf(v, __shfl_xor(v, o));
  return v;
}

// ---------------- im2col: x[B,3,224,224] -> P[B*196, 768] bf16 ----------------
__global__ __launch_bounds__(256) void im2col_bf16(const float* __restrict__ x, ushortT* __restrict__ P) {
  int i = blockIdx.x * 256 + threadIdx.x;
  const int total = BATCH * NPATCH * 768;
  if (i >= total) return;
  int k = i % 768;
  int row = i / 768;
  int c = k >> 8;
  int r = k & 255;
  int py = r >> 4, px = r & 15;
  int b = row / NPATCH;
  int p = row % NPATCH;
  int gy = p / 14, gx = p % 14;
  P[i] = f2b(x[(((size_t)b * 3 + c) * 224 + gy * 16 + py) * 224 + gx * 16 + px]);
}

// ---------------- assemble: h[b,0]=cls+pos0; h[b,1+p]=patchout+pos (f32) ----------------
__global__ __launch_bounds__(256) void assemble_kernel(const float* __restrict__ patchout,
                                                       const float* __restrict__ cls_tok,
                                                       const float* __restrict__ pos,
                                                       float* __restrict__ h) {
  int i = blockIdx.x * 256 + threadIdx.x;
  const int total = BATCH * NTOK0 * CDIM;
  if (i >= total) return;
  int c = i % CDIM;
  int n = (i / CDIM) % NTOK0;
  int b = i / (CDIM * NTOK0);
  float v = (n == 0) ? cls_tok[c] : patchout[((size_t)b * NPATCH + (n - 1)) * CDIM + c];
  h[i] = v + pos[n * CDIM + c];
}

// ---------------- weight transpose + bf16 convert: W[K][N] f32 -> Wt[N][K] bf16 ----------------
// fused per-layer: 1728 blocks covering qkv(432), proj(144), fc1(576), fc2(576)
__global__ __launch_bounds__(256) void wtrans_layer(const float* __restrict__ qkv_w, const float* __restrict__ proj_w,
                                                    const float* __restrict__ fc1_w, const float* __restrict__ fc2_w,
                                                    ushortT* __restrict__ wq, ushortT* __restrict__ wp,
                                                    ushortT* __restrict__ w1, ushortT* __restrict__ w2) {
  int id = blockIdx.x;
  const float* W; ushortT* O; int K, N, t;
  if (id < 432)       { W = qkv_w; O = wq; K = 384;  N = 1152; t = id; }
  else if (id < 576)  { W = proj_w; O = wp; K = 384; N = 384;  t = id - 432; }
  else if (id < 1152) { W = fc1_w; O = w1; K = 384;  N = 1536; t = id - 576; }
  else                { W = fc2_w; O = w2; K = 1536; N = 384;  t = id - 1152; }
  int tilesK = K >> 5;
  int k0 = (t % tilesK) << 5, n0 = (t / tilesK) << 5;
  __shared__ float tile[32][33];
  int tx = threadIdx.x & 31, ty = threadIdx.x >> 5;
  #pragma unroll
  for (int i = 0; i < 4; ++i)
    tile[ty + 8 * i][tx] = W[(size_t)(k0 + ty + 8 * i) * N + n0 + tx];
  __syncthreads();
  #pragma unroll
  for (int i = 0; i < 4; ++i)
    O[(size_t)(n0 + ty + 8 * i) * K + k0 + tx] = f2b(tile[tx][ty + 8 * i]);
}

// single matrix version (patch embed weights)
__global__ __launch_bounds__(256) void wtrans_one(const float* __restrict__ W, ushortT* __restrict__ O, int K, int N) {
  int t = blockIdx.x;
  int tilesK = K >> 5;
  int k0 = (t % tilesK) << 5, n0 = (t / tilesK) << 5;
  __shared__ float tile[32][33];
  int tx = threadIdx.x & 31, ty = threadIdx.x >> 5;
  #pragma unroll
  for (int i = 0; i < 4; ++i)
    tile[ty + 8 * i][tx] = W[(size_t)(k0 + ty + 8 * i) * N + n0 + tx];
  __syncthreads();
  #pragma unroll
  for (int i = 0; i < 4; ++i)
    O[(size_t)(n0 + ty + 8 * i) * K + k0 + tx] = f2b(tile[tx][ty + 8 * i]);
}

// ---------------- MFMA bf16 GEMM: out = act(A@W^T' + bias) [+ res] ----------------
// A: [M][K] bf16, Wt: [N][K] bf16 (pre-transposed weights), bias f32, res f32 or null.
// ACT: 0 none, 1 exact gelu. OBF: 1 -> bf16 out, 0 -> f32 out. N must be multiple of 128.
template<int ACT, int RES, int OBF>
__global__ __launch_bounds__(256) void gemm_mfma(const ushortT* __restrict__ A, const ushortT* __restrict__ Wt,
                                                 const float* __restrict__ bias, const float* __restrict__ res,
                                                 void* __restrict__ outp, int M, int N, int K) {
  __shared__ __align__(16) ushortT As[128][40];
  __shared__ __align__(16) ushortT Bs[128][40];
  const int tid = threadIdx.x;
  const int lane = tid & 63, wave = tid >> 6;
  const int wr = wave >> 1, wc = wave & 1;
  const int bm = blockIdx.y * 128, bn = blockIdx.x * 128;
  float4v acc[4][4] = {};

  const int srow = tid >> 1, sc = (tid & 1) * 16;
  const ushortT* Arow = A + (size_t)(bm + srow) * K + sc;
  const ushortT* Brow = Wt + (size_t)(bn + srow) * K + sc;
  const bool aval = (bm + srow) < M;

  for (int k0 = 0; k0 < K; k0 += 32) {
    uint4 a0 = make_uint4(0u, 0u, 0u, 0u), a1 = make_uint4(0u, 0u, 0u, 0u);
    if (aval) {
      a0 = *(const uint4*)(Arow + k0);
      a1 = *(const uint4*)(Arow + k0 + 8);
    }
    uint4 b0 = *(const uint4*)(Brow + k0);
    uint4 b1 = *(const uint4*)(Brow + k0 + 8);
    __syncthreads();  // previous iteration's frag reads complete
    *(uint4*)&As[srow][sc] = a0;
    *(uint4*)&As[srow][sc + 8] = a1;
    *(uint4*)&Bs[srow][sc] = b0;
    *(uint4*)&Bs[srow][sc + 8] = b1;
    __syncthreads();
    short8v af[4], bf[4];
    #pragma unroll
    for (int i = 0; i < 4; ++i) {
      af[i] = *(const short8v*)&As[wr * 64 + i * 16 + (lane & 15)][(lane >> 4) * 8];
      bf[i] = *(const short8v*)&Bs[wc * 64 + i * 16 + (lane & 15)][(lane >> 4) * 8];
    }
    #pragma unroll
    for (int i = 0; i < 4; ++i)
      #pragma unroll
      for (int j = 0; j < 4; ++j)
        acc[i][j] = __builtin_amdgcn_mfma_f32_16x16x32_bf16(af[i], bf[j], acc[i][j], 0, 0, 0);
  }

  const int c0 = lane & 15;
  const int r4 = (lane >> 4) * 4;
  #pragma unroll
  for (int i = 0; i < 4; ++i) {
    #pragma unroll
    for (int j = 0; j < 4; ++j) {
      const int col = bn + wc * 64 + j * 16 + c0;
      #pragma unroll
      for (int q = 0; q < 4; ++q) {
        const int row = bm + wr * 64 + i * 16 + r4 + q;
        if (row < M) {
          float v = acc[i][j][q] + bias[col];
          if (ACT == 1) v = 0.5f * v * (1.0f + erff(v * 0.70710678118654752f));
          if (RES) v += res[(size_t)row * N + col];
          if (OBF) ((ushortT*)outp)[(size_t)row * N + col] = f2b(v);
          else     ((float*)outp)[(size_t)row * N + col] = v;
        }
      }
    }
  }
}

// ---------------- layernorm f32 -> bf16 (one wave per row, C=384) ----------------
__global__ __launch_bounds__(64) void ln_bf16(const float* __restrict__ in, ushortT* __restrict__ out,
                                              const float* __restrict__ g, const float* __restrict__ bb) {
  int r = blockIdx.x;
  const float* xr = in + (size_t)r * CDIM;
  ushortT* orow = out + (size_t)r * CDIM;
  int t = threadIdx.x;
  float v[6];
  float s = 0.f;
  #pragma unroll
  for (int i = 0; i < 6; ++i) { v[i] = xr[i * 64 + t]; s += v[i]; }
  s = wave_sum(s);
  float mean = s * (1.0f / CDIM);
  float q = 0.f;
  #pragma unroll
  for (int i = 0; i < 6; ++i) { float d = v[i] - mean; q += d * d; }
  q = wave_sum(q);
  float rstd = rsqrtf(q * (1.0f / CDIM) + 1e-6f);
  #pragma unroll
  for (int i = 0; i < 6; ++i) {
    int c = i * 64 + t;
    orow[c] = f2b((v[i] - mean) * rstd * g[c] + bb[c]);
  }
}

// ---------------- layernorm f32->f32 (final norm on CLS rows) ----------------
__global__ __launch_bounds__(64) void ln_kernel(const float* __restrict__ in, float* __restrict__ out,
                                                const float* __restrict__ g, const float* __restrict__ bb,
                                                int rows, size_t in_stride, size_t out_stride) {
  int r = blockIdx.x;
  if (r >= rows) return;
  const float* xr = in + (size_t)r * in_stride;
  float* orow = out + (size_t)r * out_stride;
  int t = threadIdx.x;
  float v[6];
  float s = 0.f;
  #pragma unroll
  for (int i = 0; i < 6; ++i) { v[i] = xr[i * 64 + t]; s += v[i]; }
  s = wave_sum(s);
  float mean = s * (1.0f / CDIM);
  float q = 0.f;
  #pragma unroll
  for (int i = 0; i < 6; ++i) { float d = v[i] - mean; q += d * d; }
  q = wave_sum(q);
  float rstd = rsqrtf(q * (1.0f / CDIM) + 1e-6f);
  #pragma unroll
  for (int i = 0; i < 6; ++i) {
    int c = i * 64 + t;
    orow[c] = (v[i] - mean) * rstd * g[c] + bb[c];
  }
}

// ---------------- attention v2 ----------------
// qkv: [B,N,1152] bf16 (q at h*64, k at 384+h*64, v at 768+h*64)
// block: 128 threads (2 waves), handles 16 q-rows for one (b,h).
// K staged row-major bf16 LDS; Q staged f32; P f32 LDS per-wave; V read from global.
__global__ __launch_bounds__(128) void attn2(const ushortT* __restrict__ qkv, ushortT* __restrict__ attnout,
                                             float* __restrict__ cls_attn, int N) {
  const int h = blockIdx.y, b = blockIdx.z;
  const int rb = blockIdx.x * 16;
  const int tid = threadIdx.x;
  const int w = tid >> 6, l = tid & 63;

  __shared__ __align__(16) ushortT Ks[256][66];
  __shared__ __align__(16) float Qs[16][64];
  __shared__ __align__(16) float Pt[2][200][12];

  const size_t base = ((size_t)b * N) * 1152 + (size_t)h * 64;

  // ---- stage K rows (bf16, packed) ----
  {
    const int mrow = tid >> 3, dc = (tid & 7) * 8;
    for (int m = mrow; m < N; m += 16) {
      const uint4 kv = *(const uint4*)(qkv + base + (size_t)m * 1152 + 384 + dc);
      *(unsigned*)&Ks[m][dc + 0] = kv.x;
      *(unsigned*)&Ks[m][dc + 2] = kv.y;
      *(unsigned*)&Ks[m][dc + 4] = kv.z;
      *(unsigned*)&Ks[m][dc + 6] = kv.w;
    }
    // ---- stage Q rows (convert to f32) ----
    const int qrow = tid >> 3;
    int n = rb + qrow; if (n > N - 1) n = N - 1;
    const uint4 qv = *(const uint4*)(qkv + base + (size_t)n * 1152 + dc);
    Qs[qrow][dc + 0] = bflo(qv.x); Qs[qrow][dc + 1] = bfhi(qv.x);
    Qs[qrow][dc + 2] = bflo(qv.y); Qs[qrow][dc + 3] = bfhi(qv.y);
    Qs[qrow][dc + 4] = bflo(qv.z); Qs[qrow][dc + 5] = bfhi(qv.z);
    Qs[qrow][dc + 6] = bflo(qv.w); Qs[qrow][dc + 7] = bfhi(qv.w);
  }
  __syncthreads();

  // ---- QK^T + softmax, 2 groups of 4 rows per wave ----
  #pragma unroll
  for (int g = 0; g < 2; ++g) {
    float acc[4][4] = {};
    const int rloc = w * 8 + g * 4;
    for (int d2 = 0; d2 < 32; ++d2) {
      float kk[4][2];
      #pragma unroll
      for (int jj = 0; jj < 4; ++jj) {
        if (jj * 64 < N) {
          unsigned kv = *(const unsigned*)&Ks[l + 64 * jj][2 * d2];
          kk[jj][0] = bflo(kv); kk[jj][1] = bfhi(kv);
        }
      }
      #pragma unroll
      for (int r = 0; r < 4; ++r) {
        const float2 q2 = *(const float2*)&Qs[rloc + r][2 * d2];
        #pragma unroll
        for (int jj = 0; jj < 4; ++jj) {
          if (jj * 64 < N) {
            acc[r][jj] = fmaf(q2.x, kk[jj][0], acc[r][jj]);
            acc[r][jj] = fmaf(q2.y, kk[jj][1], acc[r][jj]);
          }
        }
      }
    }
    #pragma unroll
    for (int r = 0; r < 4; ++r) {
      float s[4];
      float mx = -INFINITY;
      #pragma unroll
      for (int jj = 0; jj < 4; ++jj) {
        const int m = l + 64 * jj;
        s[jj] = (jj * 64 < N && m < N) ? acc[r][jj] * 0.125f : -INFINITY;
        mx = fmaxf(mx, s[jj]);
      }
      mx = wave_max(mx);
      float e[4];
      float sum = 0.f;
      #pragma unroll
      for (int jj = 0; jj < 4; ++jj) { e[jj] = __expf(s[jj] - mx); sum += e[jj]; }
      sum = wave_sum(sum);
      const float inv = 1.0f / sum;
      #pragma unroll
      for (int jj = 0; jj < 4; ++jj) {
        const int m = l + 64 * jj;
        if (m < 200) Pt[w][m][g * 4 + r] = e[jj] * inv;
      }
      if (rb + rloc + r == 0) {  // CLS row probs (f32, pre-rounding)
        #pragma unroll
        for (int jj = 0; jj < 4; ++jj) {
          const int m = l + 64 * jj;
          if (m >= 1 && m < N) cls_attn[((size_t)b * NHEADS + h) * (N - 1) + (m - 1)] = e[jj] * inv;
        }
      }
    }
  }

  // ---- PV: lane owns output dim d=l; V from global (L2-resident) ----
  float accv[8] = {};
  const ushortT* vbase = qkv + base + 768 + l;
  for (int m = 0; m < N; ++m) {
    const float v = b2f(vbase[(size_t)m * 1152]);
    const float4 pa = *(const float4*)&Pt[w][m][0];
    const float4 pb = *(const float4*)&Pt[w][m][4];
    accv[0] = fmaf(pa.x, v, accv[0]);
    accv[1] = fmaf(pa.y, v, accv[1]);
    accv[2] = fmaf(pa.z, v, accv[2]);
    accv[3] = fmaf(pa.w, v, accv[3]);
    accv[4] = fmaf(pb.x, v, accv[4]);
    accv[5] = fmaf(pb.y, v, accv[5]);
    accv[6] = fmaf(pb.z, v, accv[6]);
    accv[7] = fmaf(pb.w, v, accv[7]);
  }
  #pragma unroll
  for (int r = 0; r < 8; ++r) {
    const int n = rb + w * 8 + r;
    if (n < N) attnout[((size_t)b * N + n) * CDIM + h * 64 + l] = f2b(accv[r]);
  }
}

// ---------------- CLS score = mean over heads ----------------
__global__ __launch_bounds__(256) void clsscore_kernel(const float* __restrict__ cls_attn,
                                                       float* __restrict__ scores, int Nm1) {
  int i = blockIdx.x * 256 + threadIdx.x;
  if (i >= BATCH * Nm1) return;
  int b = i / Nm1, j = i % Nm1;
  float s = 0.f;
  #pragma unroll
  for (int h = 0; h < NHEADS; ++h) s += cls_attn[((size_t)b * NHEADS + h) * Nm1 + j];
  scores[i] = s * (1.0f / NHEADS);
}

// ---------------- iterative top-k (descending, ties -> smaller index) ----------------
__global__ __launch_bounds__(256) void topk_kernel(const float* __restrict__ scores, int* __restrict__ idx,
                                                   int Nm1, int Kkeep) {
  int b = blockIdx.x;
  int t = threadIdx.x;
  __shared__ float s_sc[224];
  __shared__ float rv[256];
  __shared__ int ri[256];
  if (t < Nm1) s_sc[t] = scores[b * Nm1 + t];
  __syncthreads();
  for (int k = 0; k < Kkeep; ++k) {
    rv[t] = (t < Nm1) ? s_sc[t] : -INFINITY;
    ri[t] = t;
    __syncthreads();
    for (int s = 128; s > 0; s >>= 1) {
      if (t < s) {
        float ov = rv[t + s]; int oi = ri[t + s];
        if (ov > rv[t] || (ov == rv[t] && oi < ri[t])) { rv[t] = ov; ri[t] = oi; }
      }
      __syncthreads();
    }
    if (t == 0) {
      idx[b * Kkeep + k] = ri[0];
      s_sc[ri[0]] = -INFINITY;
    }
    __syncthreads();
  }
}

// ---------------- gather pruned tokens (f32 h) ----------------
__global__ __launch_bounds__(256) void gather_kernel(const float* __restrict__ h, const int* __restrict__ idx,
                                                     float* __restrict__ outb, int N, int Kkeep) {
  size_t total = (size_t)BATCH * (1 + Kkeep) * CDIM;
  size_t i = (size_t)blockIdx.x * 256 + threadIdx.x;
  if (i >= total) return;
  int c = (int)(i % CDIM);
  size_t r = i / CDIM;
  int n = (int)(r % (1 + Kkeep));
  int b = (int)(r / (1 + Kkeep));
  int src = (n == 0) ? 0 : 1 + idx[b * Kkeep + (n - 1)];
  outb[i] = h[((size_t)b * N + src) * CDIM + c];
}

// ---------------- small f32 GEMM (head only) ----------------
__global__ __launch_bounds__(256) void gemm_f32(const float* __restrict__ A, const float* __restrict__ W,
                                                const float* __restrict__ bias, float* __restrict__ out,
                                                int M, int N, int K) {
  __shared__ __align__(16) float As[16][64];
  __shared__ __align__(16) float Ws[16][64];
  const int tid = threadIdx.x;
  const int tx = tid & 15, ty = tid >> 4;
  const int bm = blockIdx.y * 64, bn = blockIdx.x * 64;
  float acc[4][4] = {};
  const int ma = tid >> 2;
  const int ka = (tid & 3) << 2;
  const int kw = ty;
  const int nw = tx << 2;
  for (int k0 = 0; k0 < K; k0 += 16) {
    {
      float4 a4 = make_float4(0.f, 0.f, 0.f, 0.f);
      if (bm + ma < M) a4 = *reinterpret_cast<const float4*>(&A[(size_t)(bm + ma) * K + k0 + ka]);
      As[ka + 0][ma] = a4.x; As[ka + 1][ma] = a4.y; As[ka + 2][ma] = a4.z; As[ka + 3][ma] = a4.w;
    }
    {
      const int gn = bn + nw;
      const float* wp = &W[(size_t)(k0 + kw) * N + gn];
      #pragma unroll
      for (int j = 0; j < 4; ++j) Ws[kw][nw + j] = (gn + j < N) ? wp[j] : 0.f;
    }
    __syncthreads();
    #pragma unroll
    for (int kk = 0; kk < 16; ++kk) {
      float4 a = *reinterpret_cast<const float4*>(&As[kk][ty << 2]);
      float4 w = *reinterpret_cast<const float4*>(&Ws[kk][tx << 2]);
      float av[4] = {a.x, a.y, a.z, a.w};
      float wv[4] = {w.x, w.y, w.z, w.w};
      #pragma unroll
      for (int i = 0; i < 4; ++i)
        #pragma unroll
        for (int j = 0; j < 4; ++j)
          acc[i][j] = fmaf(av[i], wv[j], acc[i][j]);
    }
    __syncthreads();
  }
  #pragma unroll
  for (int i = 0; i < 4; ++i) {
    int r = bm + (ty << 2) + i;
    if (r >= M) continue;
    #pragma unroll
    for (int j = 0; j < 4; ++j) {
      int cidx = bn + (tx << 2) + j;
      if (cidx >= N) continue;
      out[(size_t)r * N + cidx] = acc[i][j] + bias[cidx];
    }
  }
}

// ---------------- host launch ----------------
extern "C" void kernel_launch(void* const* d_in, const int* in_sizes, int n_in,
                              void* d_out, int out_size, void* d_ws, size_t ws_size,
                              hipStream_t stream) {
  const float* x        = (const float*)d_in[0];
  const float* patch_w  = (const float*)d_in[1];
  const float* patch_b  = (const float*)d_in[2];
  const float* cls_tok  = (const float*)d_in[3];
  const float* pos      = (const float*)d_in[4];
  const float* ln1_g    = (const float*)d_in[5];
  const float* ln1_b    = (const float*)d_in[6];
  const float* qkv_w    = (const float*)d_in[7];
  const float* qkv_b    = (const float*)d_in[8];
  const float* proj_w   = (const float*)d_in[9];
  const float* proj_b   = (const float*)d_in[10];
  const float* ln2_g    = (const float*)d_in[11];
  const float* ln2_b    = (const float*)d_in[12];
  const float* fc1_w    = (const float*)d_in[13];
  const float* fc1_b    = (const float*)d_in[14];
  const float* fc2_w    = (const float*)d_in[15];
  const float* fc2_b    = (const float*)d_in[16];
  const float* norm_g   = (const float*)d_in[17];
  const float* norm_b   = (const float*)d_in[18];
  const float* head_w   = (const float*)d_in[19];
  const float* head_b   = (const float*)d_in[20];
  float* out = (float*)d_out;

  float* ws = (float*)d_ws;
  // ---- workspace layout (float offsets) ----
  float* h        = ws;                          // 4,841,472 f32 [B,197,C]
  float* big      = ws + 4841472;                // 14,524,416 f (im2col bf16 / patchout f32 / qkv bf16 / hidden bf16 / gather tmp)
  ushortT* big_u  = (ushortT*)big;
  float* patchout = big + 4816896;               // f32 [12544,384] (coexists with im2col bf16 at big)
  ushortT* lnb_u  = (ushortT*)(ws + 19365888);   // [M,384] bf16
  ushortT* attn_u = (ushortT*)(ws + 21786624);   // [M,384] bf16
  ushortT* wbuf_u = (ushortT*)(ws + 24207360);   // 1,769,472 ushorts (per-layer weights bf16 transposed)
  float* cls_attn = ws + 25092096;               // 75,264
  float* scores   = ws + 25167360;               // 12,544
  int*   idxbuf   = (int*)(ws + 25179904);       // 11,264 ints
  float* cls0     = ws + 25191168;               // 24,576

  ushortT* wq = wbuf_u;
  ushortT* wp = wbuf_u + 442368;
  ushortT* w1 = wbuf_u + 589824;
  ushortT* w2 = wbuf_u + 1179648;

  // ---- patch embed ----
  {
    int total = BATCH * NPATCH * 768;
    im2col_bf16<<<(total + 255) / 256, 256, 0, stream>>>(x, big_u);
    wtrans_one<<<288, 256, 0, stream>>>(patch_w, wbuf_u, 768, CDIM);
    gemm_mfma<0, 0, 0><<<dim3(3, 98), 256, 0, stream>>>(big_u, wbuf_u, patch_b, nullptr, patchout,
                                                        BATCH * NPATCH, CDIM, 768);
    int tot2 = BATCH * NTOK0 * CDIM;
    assemble_kernel<<<(tot2 + 255) / 256, 256, 0, stream>>>(patchout, cls_tok, pos, h);
  }

  int ncur = NTOK0;
  for (int i = 0; i < NLAYERS; ++i) {
    int M = BATCH * ncur;
    int gy = (M + 127) / 128;
    // per-layer weight convert+transpose
    wtrans_layer<<<1728, 256, 0, stream>>>(qkv_w + (size_t)i * CDIM * 3 * CDIM,
                                           proj_w + (size_t)i * CDIM * CDIM,
                                           fc1_w + (size_t)i * CDIM * MLPD,
                                           fc2_w + (size_t)i * MLPD * CDIM,
                                           wq, wp, w1, w2);
    // LN1 -> bf16
    ln_bf16<<<M, 64, 0, stream>>>(h, lnb_u, ln1_g + i * CDIM, ln1_b + i * CDIM);
    // QKV GEMM -> bf16
    gemm_mfma<0, 0, 1><<<dim3(9, gy), 256, 0, stream>>>(lnb_u, wq, qkv_b + i * 3 * CDIM, nullptr,
                                                        big_u, M, 3 * CDIM, CDIM);
    // attention
    attn2<<<dim3((ncur + 15) / 16, NHEADS, BATCH), 128, 0, stream>>>(big_u, attn_u, cls_attn, ncur);
    // proj + residual (f32 h in place)
    gemm_mfma<0, 1, 0><<<dim3(3, gy), 256, 0, stream>>>(attn_u, wp, proj_b + i * CDIM, h,
                                                        h, M, CDIM, CDIM);
    // prune
    if (i == 2 || i == 4 || i == 6) {
      int keep = (i == 2) ? 176 : (i == 4) ? 149 : 119;
      int Nm1 = ncur - 1;
      int tot = BATCH * Nm1;
      clsscore_kernel<<<(tot + 255) / 256, 256, 0, stream>>>(cls_attn, scores, Nm1);
      topk_kernel<<<BATCH, 256, 0, stream>>>(scores, idxbuf, Nm1, keep);
      int newN = 1 + keep;
      size_t gtot = (size_t)BATCH * newN * CDIM;
      gather_kernel<<<(int)((gtot + 255) / 256), 256, 0, stream>>>(h, idxbuf, big, ncur, keep);
      hipMemcpyAsync(h, big, gtot * sizeof(float), hipMemcpyDeviceToDevice, stream);
      ncur = newN;
      M = BATCH * ncur;
      gy = (M + 127) / 128;
    }
    // LN2 -> bf16
    ln_bf16<<<M, 64, 0, stream>>>(h, lnb_u, ln2_g + i * CDIM, ln2_b + i * CDIM);
    // FC1 + gelu -> bf16 hidden (big)
    gemm_mfma<1, 0, 1><<<dim3(12, gy), 256, 0, stream>>>(lnb_u, w1, fc1_b + i * MLPD, nullptr,
                                                         big_u, M, MLPD, CDIM);
    // FC2 + residual -> f32 h
    gemm_mfma<0, 1, 0><<<dim3(3, gy), 256, 0, stream>>>(big_u, w2, fc2_b + i * CDIM, h,
                                                        h, M, CDIM, MLPD);
  }

  // final LN of CLS rows only, then head
  ln_kernel<<<BATCH, 64, 0, stream>>>(h, cls0, norm_g, norm_b, BATCH, (size_t)ncur * CDIM, CDIM);
  gemm_f32<<<dim3(2, 1), 256, 0, stream>>>(cls0, head_w, head_b, out, BATCH, NCLS, CDIM);
}

// Round 3
// 3317.881 us; speedup vs baseline: 4.2888x; 1.9726x over previous
//
#include <hip/hip_runtime.h>
#include <hip/hip_bf16.h>
#include <math.h>

// ---------------- model constants ----------------
#define BATCH 64
#define CDIM 384
#define NHEADS 6
#define HD 64
#define MLPD 1536
#define NLAYERS 12
#define NPATCH 196
#define NTOK0 197
#define NCLS 100

typedef unsigned short ushortT;
typedef __attribute__((ext_vector_type(8))) short short8v;
typedef __attribute__((ext_vector_type(4))) float float4v;

// ---------------- bf16 helpers ----------------
__device__ inline ushortT f2b(float f) {
  union { float f; unsigned u; } x; x.f = f;
  unsigned r = x.u + 0x7fffu + ((x.u >> 16) & 1u);
  return (ushortT)(r >> 16);
}
__device__ inline float b2f(ushortT u) {
  union { unsigned u; float f; } x; x.u = ((unsigned)u) << 16;
  return x.f;
}

// ---------------- wave helpers ----------------
__device__ inline float wave_sum(float v) {
  #pragma unroll
  for (int o = 32; o > 0; o >>= 1) v += __shfl_xor(v, o);
  return v;
}

// ---------------- im2col: x[B,3,224,224] -> P[B*196, 768] bf16 ----------------
__global__ __launch_bounds__(256) void im2col_bf16(const float* __restrict__ x, ushortT* __restrict__ P) {
  int i = blockIdx.x * 256 + threadIdx.x;
  const int total = BATCH * NPATCH * 768;
  if (i >= total) return;
  int k = i % 768;
  int row = i / 768;
  int c = k >> 8;
  int r = k & 255;
  int py = r >> 4, px = r & 15;
  int b = row / NPATCH;
  int p = row % NPATCH;
  int gy = p / 14, gx = p % 14;
  P[i] = f2b(x[(((size_t)b * 3 + c) * 224 + gy * 16 + py) * 224 + gx * 16 + px]);
}

// ---------------- assemble: h[b,0]=cls+pos0; h[b,1+p]=patchout+pos (f32) ----------------
__global__ __launch_bounds__(256) void assemble_kernel(const float* __restrict__ patchout,
                                                       const float* __restrict__ cls_tok,
                                                       const float* __restrict__ pos,
                                                       float* __restrict__ h) {
  int i = blockIdx.x * 256 + threadIdx.x;
  const int total = BATCH * NTOK0 * CDIM;
  if (i >= total) return;
  int c = i % CDIM;
  int n = (i / CDIM) % NTOK0;
  int b = i / (CDIM * NTOK0);
  float v = (n == 0) ? cls_tok[c] : patchout[((size_t)b * NPATCH + (n - 1)) * CDIM + c];
  h[i] = v + pos[n * CDIM + c];
}

// ---------------- weight transpose + bf16 convert: W[K][N] f32 -> Wt[N][K] bf16 ----------------
__global__ __launch_bounds__(256) void wtrans_layer(const float* __restrict__ qkv_w, const float* __restrict__ proj_w,
                                                    const float* __restrict__ fc1_w, const float* __restrict__ fc2_w,
                                                    ushortT* __restrict__ wq, ushortT* __restrict__ wp,
                                                    ushortT* __restrict__ w1, ushortT* __restrict__ w2) {
  int id = blockIdx.x;
  const float* W; ushortT* O; int K, N, t;
  if (id < 432)       { W = qkv_w; O = wq; K = 384;  N = 1152; t = id; }
  else if (id < 576)  { W = proj_w; O = wp; K = 384; N = 384;  t = id - 432; }
  else if (id < 1152) { W = fc1_w; O = w1; K = 384;  N = 1536; t = id - 576; }
  else                { W = fc2_w; O = w2; K = 1536; N = 384;  t = id - 1152; }
  int tilesK = K >> 5;
  int k0 = (t % tilesK) << 5, n0 = (t / tilesK) << 5;
  __shared__ float tile[32][33];
  int tx = threadIdx.x & 31, ty = threadIdx.x >> 5;
  #pragma unroll
  for (int i = 0; i < 4; ++i)
    tile[ty + 8 * i][tx] = W[(size_t)(k0 + ty + 8 * i) * N + n0 + tx];
  __syncthreads();
  #pragma unroll
  for (int i = 0; i < 4; ++i)
    O[(size_t)(n0 + ty + 8 * i) * K + k0 + tx] = f2b(tile[tx][ty + 8 * i]);
}

// single matrix version (patch embed weights)
__global__ __launch_bounds__(256) void wtrans_one(const float* __restrict__ W, ushortT* __restrict__ O, int K, int N) {
  int t = blockIdx.x;
  int tilesK = K >> 5;
  int k0 = (t % tilesK) << 5, n0 = (t / tilesK) << 5;
  __shared__ float tile[32][33];
  int tx = threadIdx.x & 31, ty = threadIdx.x >> 5;
  #pragma unroll
  for (int i = 0; i < 4; ++i)
    tile[ty + 8 * i][tx] = W[(size_t)(k0 + ty + 8 * i) * N + n0 + tx];
  __syncthreads();
  #pragma unroll
  for (int i = 0; i < 4; ++i)
    O[(size_t)(n0 + ty + 8 * i) * K + k0 + tx] = f2b(tile[tx][ty + 8 * i]);
}

// ---------------- MFMA bf16 GEMM: out = act(A@Wt^T + bias) [+ res] ----------------
template<int ACT, int RES, int OBF>
__global__ __launch_bounds__(256) void gemm_mfma(const ushortT* __restrict__ A, const ushortT* __restrict__ Wt,
                                                 const float* __restrict__ bias, const float* __restrict__ res,
                                                 void* __restrict__ outp, int M, int N, int K) {
  __shared__ __align__(16) ushortT As[128][40];
  __shared__ __align__(16) ushortT Bs[128][40];
  const int tid = threadIdx.x;
  const int lane = tid & 63, wave = tid >> 6;
  const int wr = wave >> 1, wc = wave & 1;
  const int bm = blockIdx.y * 128, bn = blockIdx.x * 128;
  float4v acc[4][4] = {};

  const int srow = tid >> 1, sc = (tid & 1) * 16;
  const ushortT* Arow = A + (size_t)(bm + srow) * K + sc;
  const ushortT* Brow = Wt + (size_t)(bn + srow) * K + sc;
  const bool aval = (bm + srow) < M;

  for (int k0 = 0; k0 < K; k0 += 32) {
    uint4 a0 = make_uint4(0u, 0u, 0u, 0u), a1 = make_uint4(0u, 0u, 0u, 0u);
    if (aval) {
      a0 = *(const uint4*)(Arow + k0);
      a1 = *(const uint4*)(Arow + k0 + 8);
    }
    uint4 b0 = *(const uint4*)(Brow + k0);
    uint4 b1 = *(const uint4*)(Brow + k0 + 8);
    __syncthreads();
    *(uint4*)&As[srow][sc] = a0;
    *(uint4*)&As[srow][sc + 8] = a1;
    *(uint4*)&Bs[srow][sc] = b0;
    *(uint4*)&Bs[srow][sc + 8] = b1;
    __syncthreads();
    short8v af[4], bf[4];
    #pragma unroll
    for (int i = 0; i < 4; ++i) {
      af[i] = *(const short8v*)&As[wr * 64 + i * 16 + (lane & 15)][(lane >> 4) * 8];
      bf[i] = *(const short8v*)&Bs[wc * 64 + i * 16 + (lane & 15)][(lane >> 4) * 8];
    }
    #pragma unroll
    for (int i = 0; i < 4; ++i)
      #pragma unroll
      for (int j = 0; j < 4; ++j)
        acc[i][j] = __builtin_amdgcn_mfma_f32_16x16x32_bf16(af[i], bf[j], acc[i][j], 0, 0, 0);
  }

  const int c0 = lane & 15;
  const int r4 = (lane >> 4) * 4;
  #pragma unroll
  for (int i = 0; i < 4; ++i) {
    #pragma unroll
    for (int j = 0; j < 4; ++j) {
      const int col = bn + wc * 64 + j * 16 + c0;
      #pragma unroll
      for (int q = 0; q < 4; ++q) {
        const int row = bm + wr * 64 + i * 16 + r4 + q;
        if (row < M) {
          float v = acc[i][j][q] + bias[col];
          if (ACT == 1) v = 0.5f * v * (1.0f + erff(v * 0.70710678118654752f));
          if (RES) v += res[(size_t)row * N + col];
          if (OBF) ((ushortT*)outp)[(size_t)row * N + col] = f2b(v);
          else     ((float*)outp)[(size_t)row * N + col] = v;
        }
      }
    }
  }
}

// ---------------- layernorm f32 -> bf16 (one wave per row, C=384) ----------------
__global__ __launch_bounds__(64) void ln_bf16(const float* __restrict__ in, ushortT* __restrict__ out,
                                              const float* __restrict__ g, const float* __restrict__ bb) {
  int r = blockIdx.x;
  const float* xr = in + (size_t)r * CDIM;
  ushortT* orow = out + (size_t)r * CDIM;
  int t = threadIdx.x;
  float v[6];
  float s = 0.f;
  #pragma unroll
  for (int i = 0; i < 6; ++i) { v[i] = xr[i * 64 + t]; s += v[i]; }
  s = wave_sum(s);
  float mean = s * (1.0f / CDIM);
  float q = 0.f;
  #pragma unroll
  for (int i = 0; i < 6; ++i) { float d = v[i] - mean; q += d * d; }
  q = wave_sum(q);
  float rstd = rsqrtf(q * (1.0f / CDIM) + 1e-6f);
  #pragma unroll
  for (int i = 0; i < 6; ++i) {
    int c = i * 64 + t;
    orow[c] = f2b((v[i] - mean) * rstd * g[c] + bb[c]);
  }
}

// ---------------- layernorm f32->f32 ----------------
__global__ __launch_bounds__(64) void ln_kernel(const float* __restrict__ in, float* __restrict__ out,
                                                const float* __restrict__ g, const float* __restrict__ bb,
                                                int rows, size_t in_stride, size_t out_stride) {
  int r = blockIdx.x;
  if (r >= rows) return;
  const float* xr = in + (size_t)r * in_stride;
  float* orow = out + (size_t)r * out_stride;
  int t = threadIdx.x;
  float v[6];
  float s = 0.f;
  #pragma unroll
  for (int i = 0; i < 6; ++i) { v[i] = xr[i * 64 + t]; s += v[i]; }
  s = wave_sum(s);
  float mean = s * (1.0f / CDIM);
  float q = 0.f;
  #pragma unroll
  for (int i = 0; i < 6; ++i) { float d = v[i] - mean; q += d * d; }
  q = wave_sum(q);
  float rstd = rsqrtf(q * (1.0f / CDIM) + 1e-6f);
  #pragma unroll
  for (int i = 0; i < 6; ++i) {
    int c = i * 64 + t;
    orow[c] = (v[i] - mean) * rstd * g[c] + bb[c];
  }
}

// ---------------- attention v3: MFMA ----------------
// qkv: [B,N,1152] bf16 (q at h*64, k at 384+h*64, v at 768+h*64)
// block: 256 threads (4 waves), one (b,h), 64 q-rows; wave w owns q-rows [rb+16w, rb+16w+16).
// KS = number of 32-wide k-steps (KT = 32*KS >= N). NT = 2*KS 16-wide S col-tiles.
template<int KS>
__global__ __launch_bounds__(256) void attn3(const ushortT* __restrict__ qkv, ushortT* __restrict__ attnout,
                                             float* __restrict__ cls_attn, int N) {
  constexpr int NT = 2 * KS;
  constexpr int KT = 32 * KS;
  const int h = blockIdx.y, b = blockIdx.z;
  const int rb = blockIdx.x * 64;
  const int tid = threadIdx.x;
  const int w = tid >> 6, l = tid & 63;
  const int c = l & 15, g = l >> 4;

  __shared__ __align__(16) ushortT Vt[64][232];      // V^T: [dim][token]
  __shared__ __align__(16) ushortT Ps[4][16][232];   // per-wave P (bf16), rows=q, cols=k

  const ushortT* bq = qkv + (size_t)(b * N) * 1152 + (size_t)h * 64;

  // ---- stage V transposed (coalesced global read, b16 scatter to LDS) ----
  {
    const int vr = tid >> 3, vc = (tid & 7) * 8;
    for (int p = 0; p < KT; p += 32) {
      const int m = vr + p;
      if (m < N) {
        short8v v8 = *(const short8v*)(bq + (size_t)m * 1152 + 768 + vc);
        #pragma unroll
        for (int j = 0; j < 8; ++j) Vt[vc + j][m] = (ushortT)v8[j];
      } else if (m < KT) {
        #pragma unroll
        for (int j = 0; j < 8; ++j) Vt[vc + j][m] = 0;
      }
    }
  }
  __syncthreads();

  // ---- Q A-fragments from global (per wave: rows rb+16w+c, 2 k-halves) ----
  short8v qf0, qf1;
  {
    int row = rb + 16 * w + c; if (row >= N) row = N - 1;
    const ushortT* qrow = bq + (size_t)row * 1152;
    qf0 = *(const short8v*)(qrow + g * 8);
    qf1 = *(const short8v*)(qrow + 32 + g * 8);
  }

  // ---- S = Q@K^T : B-fragments straight from global K rows ----
  float4v sc[NT];
  #pragma unroll
  for (int kt = 0; kt < NT; ++kt) {
    int krow = 16 * kt + c; if (krow >= N) krow = N - 1;
    const ushortT* kr = bq + (size_t)krow * 1152 + 384;
    short8v b0 = *(const short8v*)(kr + g * 8);
    short8v b1 = *(const short8v*)(kr + 32 + g * 8);
    float4v a = {};
    a = __builtin_amdgcn_mfma_f32_16x16x32_bf16(qf0, b0, a, 0, 0, 0);
    a = __builtin_amdgcn_mfma_f32_16x16x32_bf16(qf1, b1, a, 0, 0, 0);
    sc[kt] = a;
  }

  // ---- softmax over k (C-frag: col=16kt+c -> k, row=4g+q -> q-row) ----
  float m4[4] = {-INFINITY, -INFINITY, -INFINITY, -INFINITY};
  #pragma unroll
  for (int kt = 0; kt < NT; ++kt) {
    const bool valid = (16 * kt + c) < N;
    #pragma unroll
    for (int q = 0; q < 4; ++q) {
      float s = valid ? sc[kt][q] * 0.125f : -INFINITY;
      sc[kt][q] = s;
      m4[q] = fmaxf(m4[q], s);
    }
  }
  #pragma unroll
  for (int q = 0; q < 4; ++q) {
    #pragma unroll
    for (int o = 1; o <= 8; o <<= 1) m4[q] = fmaxf(m4[q], __shfl_xor(m4[q], o));
  }
  float sum4[4] = {0.f, 0.f, 0.f, 0.f};
  #pragma unroll
  for (int kt = 0; kt < NT; ++kt) {
    #pragma unroll
    for (int q = 0; q < 4; ++q) {
      float e = __expf(sc[kt][q] - m4[q]);
      sc[kt][q] = e;
      sum4[q] += e;
    }
  }
  #pragma unroll
  for (int q = 0; q < 4; ++q) {
    #pragma unroll
    for (int o = 1; o <= 8; o <<= 1) sum4[q] += __shfl_xor(sum4[q], o);
  }
  float inv4[4];
  #pragma unroll
  for (int q = 0; q < 4; ++q) inv4[q] = 1.0f / sum4[q];

  // ---- write P (unnormalized e, bf16) to per-wave LDS ----
  #pragma unroll
  for (int kt = 0; kt < NT; ++kt) {
    #pragma unroll
    for (int q = 0; q < 4; ++q) Ps[w][4 * g + q][16 * kt + c] = f2b(sc[kt][q]);
  }

  // ---- CLS attention probs (q-row 0 lives in block rb=0, wave 0, group 0) ----
  if (rb == 0 && w == 0 && g == 0) {
    const float inv0 = inv4[0];
    #pragma unroll
    for (int kt = 0; kt < NT; ++kt) {
      const int col = 16 * kt + c;
      if (col >= 1 && col < N)
        cls_attn[((size_t)b * NHEADS + h) * (N - 1) + (col - 1)] = sc[kt][0] * inv0;
    }
  }

  // ---- O = P @ V  (A-frag from Ps, B-frag from Vt rows=dims) ----
  float4v oacc[4] = {};
  #pragma unroll
  for (int s2 = 0; s2 < KS; ++s2) {
    short8v pa = *(const short8v*)&Ps[w][c][32 * s2 + 8 * g];
    #pragma unroll
    for (int nt = 0; nt < 4; ++nt) {
      short8v vb = *(const short8v*)&Vt[16 * nt + c][32 * s2 + 8 * g];
      oacc[nt] = __builtin_amdgcn_mfma_f32_16x16x32_bf16(pa, vb, oacc[nt], 0, 0, 0);
    }
  }

  // ---- epilogue: scale by 1/sum, write bf16 (row=4g+q, col=16nt+c) ----
  #pragma unroll
  for (int nt = 0; nt < 4; ++nt) {
    #pragma unroll
    for (int q = 0; q < 4; ++q) {
      const int row = rb + 16 * w + 4 * g + q;
      if (row < N)
        attnout[((size_t)(b * N + row)) * CDIM + h * 64 + 16 * nt + c] = f2b(oacc[nt][q] * inv4[q]);
    }
  }
}

// ---------------- CLS score = mean over heads ----------------
__global__ __launch_bounds__(256) void clsscore_kernel(const float* __restrict__ cls_attn,
                                                       float* __restrict__ scores, int Nm1) {
  int i = blockIdx.x * 256 + threadIdx.x;
  if (i >= BATCH * Nm1) return;
  int b = i / Nm1, j = i % Nm1;
  float s = 0.f;
  #pragma unroll
  for (int h = 0; h < NHEADS; ++h) s += cls_attn[((size_t)b * NHEADS + h) * Nm1 + j];
  scores[i] = s * (1.0f / NHEADS);
}

// ---------------- iterative top-k (descending, ties -> smaller index) ----------------
__global__ __launch_bounds__(256) void topk_kernel(const float* __restrict__ scores, int* __restrict__ idx,
                                                   int Nm1, int Kkeep) {
  int b = blockIdx.x;
  int t = threadIdx.x;
  __shared__ float s_sc[224];
  __shared__ float rv[256];
  __shared__ int ri[256];
  if (t < Nm1) s_sc[t] = scores[b * Nm1 + t];
  __syncthreads();
  for (int k = 0; k < Kkeep; ++k) {
    rv[t] = (t < Nm1) ? s_sc[t] : -INFINITY;
    ri[t] = t;
    __syncthreads();
    for (int s = 128; s > 0; s >>= 1) {
      if (t < s) {
        float ov = rv[t + s]; int oi = ri[t + s];
        if (ov > rv[t] || (ov == rv[t] && oi < ri[t])) { rv[t] = ov; ri[t] = oi; }
      }
      __syncthreads();
    }
    if (t == 0) {
      idx[b * Kkeep + k] = ri[0];
      s_sc[ri[0]] = -INFINITY;
    }
    __syncthreads();
  }
}

// ---------------- gather pruned tokens (f32 h) ----------------
__global__ __launch_bounds__(256) void gather_kernel(const float* __restrict__ h, const int* __restrict__ idx,
                                                     float* __restrict__ outb, int N, int Kkeep) {
  size_t total = (size_t)BATCH * (1 + Kkeep) * CDIM;
  size_t i = (size_t)blockIdx.x * 256 + threadIdx.x;
  if (i >= total) return;
  int c = (int)(i % CDIM);
  size_t r = i / CDIM;
  int n = (int)(r % (1 + Kkeep));
  int b = (int)(r / (1 + Kkeep));
  int src = (n == 0) ? 0 : 1 + idx[b * Kkeep + (n - 1)];
  outb[i] = h[((size_t)b * N + src) * CDIM + c];
}

// ---------------- small f32 GEMM (head only) ----------------
__global__ __launch_bounds__(256) void gemm_f32(const float* __restrict__ A, const float* __restrict__ W,
                                                const float* __restrict__ bias, float* __restrict__ out,
                                                int M, int N, int K) {
  __shared__ __align__(16) float As[16][64];
  __shared__ __align__(16) float Ws[16][64];
  const int tid = threadIdx.x;
  const int tx = tid & 15, ty = tid >> 4;
  const int bm = blockIdx.y * 64, bn = blockIdx.x * 64;
  float acc[4][4] = {};
  const int ma = tid >> 2;
  const int ka = (tid & 3) << 2;
  const int kw = ty;
  const int nw = tx << 2;
  for (int k0 = 0; k0 < K; k0 += 16) {
    {
      float4 a4 = make_float4(0.f, 0.f, 0.f, 0.f);
      if (bm + ma < M) a4 = *reinterpret_cast<const float4*>(&A[(size_t)(bm + ma) * K + k0 + ka]);
      As[ka + 0][ma] = a4.x; As[ka + 1][ma] = a4.y; As[ka + 2][ma] = a4.z; As[ka + 3][ma] = a4.w;
    }
    {
      const int gn = bn + nw;
      const float* wp = &W[(size_t)(k0 + kw) * N + gn];
      #pragma unroll
      for (int j = 0; j < 4; ++j) Ws[kw][nw + j] = (gn + j < N) ? wp[j] : 0.f;
    }
    __syncthreads();
    #pragma unroll
    for (int kk = 0; kk < 16; ++kk) {
      float4 a = *reinterpret_cast<const float4*>(&As[kk][ty << 2]);
      float4 w = *reinterpret_cast<const float4*>(&Ws[kk][tx << 2]);
      float av[4] = {a.x, a.y, a.z, a.w};
      float wv[4] = {w.x, w.y, w.z, w.w};
      #pragma unroll
      for (int i = 0; i < 4; ++i)
        #pragma unroll
        for (int j = 0; j < 4; ++j)
          acc[i][j] = fmaf(av[i], wv[j], acc[i][j]);
    }
    __syncthreads();
  }
  #pragma unroll
  for (int i = 0; i < 4; ++i) {
    int r = bm + (ty << 2) + i;
    if (r >= M) continue;
    #pragma unroll
    for (int j = 0; j < 4; ++j) {
      int cidx = bn + (tx << 2) + j;
      if (cidx >= N) continue;
      out[(size_t)r * N + cidx] = acc[i][j] + bias[cidx];
    }
  }
}

// ---------------- host launch ----------------
extern "C" void kernel_launch(void* const* d_in, const int* in_sizes, int n_in,
                              void* d_out, int out_size, void* d_ws, size_t ws_size,
                              hipStream_t stream) {
  const float* x        = (const float*)d_in[0];
  const float* patch_w  = (const float*)d_in[1];
  const float* patch_b  = (const float*)d_in[2];
  const float* cls_tok  = (const float*)d_in[3];
  const float* pos      = (const float*)d_in[4];
  const float* ln1_g    = (const float*)d_in[5];
  const float* ln1_b    = (const float*)d_in[6];
  const float* qkv_w    = (const float*)d_in[7];
  const float* qkv_b    = (const float*)d_in[8];
  const float* proj_w   = (const float*)d_in[9];
  const float* proj_b   = (const float*)d_in[10];
  const float* ln2_g    = (const float*)d_in[11];
  const float* ln2_b    = (const float*)d_in[12];
  const float* fc1_w    = (const float*)d_in[13];
  const float* fc1_b    = (const float*)d_in[14];
  const float* fc2_w    = (const float*)d_in[15];
  const float* fc2_b    = (const float*)d_in[16];
  const float* norm_g   = (const float*)d_in[17];
  const float* norm_b   = (const float*)d_in[18];
  const float* head_w   = (const float*)d_in[19];
  const float* head_b   = (const float*)d_in[20];
  float* out = (float*)d_out;

  float* ws = (float*)d_ws;
  float* h        = ws;                          // 4,841,472 f32 [B,197,C]
  float* big      = ws + 4841472;                // im2col bf16 / patchout f32 / qkv bf16 / hidden bf16 / gather tmp
  ushortT* big_u  = (ushortT*)big;
  float* patchout = big + 4816896;
  ushortT* lnb_u  = (ushortT*)(ws + 19365888);
  ushortT* attn_u = (ushortT*)(ws + 21786624);
  ushortT* wbuf_u = (ushortT*)(ws + 24207360);
  float* cls_attn = ws + 25092096;
  float* scores   = ws + 25167360;
  int*   idxbuf   = (int*)(ws + 25179904);
  float* cls0     = ws + 25191168;

  ushortT* wq = wbuf_u;
  ushortT* wp = wbuf_u + 442368;
  ushortT* w1 = wbuf_u + 589824;
  ushortT* w2 = wbuf_u + 1179648;

  // ---- patch embed ----
  {
    int total = BATCH * NPATCH * 768;
    im2col_bf16<<<(total + 255) / 256, 256, 0, stream>>>(x, big_u);
    wtrans_one<<<288, 256, 0, stream>>>(patch_w, wbuf_u, 768, CDIM);
    gemm_mfma<0, 0, 0><<<dim3(3, 98), 256, 0, stream>>>(big_u, wbuf_u, patch_b, nullptr, patchout,
                                                        BATCH * NPATCH, CDIM, 768);
    int tot2 = BATCH * NTOK0 * CDIM;
    assemble_kernel<<<(tot2 + 255) / 256, 256, 0, stream>>>(patchout, cls_tok, pos, h);
  }

  int ncur = NTOK0;
  for (int i = 0; i < NLAYERS; ++i) {
    int M = BATCH * ncur;
    int gy = (M + 127) / 128;
    wtrans_layer<<<1728, 256, 0, stream>>>(qkv_w + (size_t)i * CDIM * 3 * CDIM,
                                           proj_w + (size_t)i * CDIM * CDIM,
                                           fc1_w + (size_t)i * CDIM * MLPD,
                                           fc2_w + (size_t)i * MLPD * CDIM,
                                           wq, wp, w1, w2);
    ln_bf16<<<M, 64, 0, stream>>>(h, lnb_u, ln1_g + i * CDIM, ln1_b + i * CDIM);
    gemm_mfma<0, 0, 1><<<dim3(9, gy), 256, 0, stream>>>(lnb_u, wq, qkv_b + i * 3 * CDIM, nullptr,
                                                        big_u, M, 3 * CDIM, CDIM);
    // attention (MFMA)
    {
      dim3 g((ncur + 63) / 64, NHEADS, BATCH);
      int ks = (ncur + 31) / 32;
      if (ks == 7)      attn3<7><<<g, 256, 0, stream>>>(big_u, attn_u, cls_attn, ncur);
      else if (ks == 6) attn3<6><<<g, 256, 0, stream>>>(big_u, attn_u, cls_attn, ncur);
      else if (ks == 5) attn3<5><<<g, 256, 0, stream>>>(big_u, attn_u, cls_attn, ncur);
      else              attn3<4><<<g, 256, 0, stream>>>(big_u, attn_u, cls_attn, ncur);
    }
    gemm_mfma<0, 1, 0><<<dim3(3, gy), 256, 0, stream>>>(attn_u, wp, proj_b + i * CDIM, h,
                                                        h, M, CDIM, CDIM);
    if (i == 2 || i == 4 || i == 6) {
      int keep = (i == 2) ? 176 : (i == 4) ? 149 : 119;
      int Nm1 = ncur - 1;
      int tot = BATCH * Nm1;
      clsscore_kernel<<<(tot + 255) / 256, 256, 0, stream>>>(cls_attn, scores, Nm1);
      topk_kernel<<<BATCH, 256, 0, stream>>>(scores, idxbuf, Nm1, keep);
      int newN = 1 + keep;
      size_t gtot = (size_t)BATCH * newN * CDIM;
      gather_kernel<<<(int)((gtot + 255) / 256), 256, 0, stream>>>(h, idxbuf, big, ncur, keep);
      hipMemcpyAsync(h, big, gtot * sizeof(float), hipMemcpyDeviceToDevice, stream);
      ncur = newN;
      M = BATCH * ncur;
      gy = (M + 127) / 128;
    }
    ln_bf16<<<M, 64, 0, stream>>>(h, lnb_u, ln2_g + i * CDIM, ln2_b + i * CDIM);
    gemm_mfma<1, 0, 1><<<dim3(12, gy), 256, 0, stream>>>(lnb_u, w1, fc1_b + i * MLPD, nullptr,
                                                         big_u, M, MLPD, CDIM);
    gemm_mfma<0, 1, 0><<<dim3(3, gy), 256, 0, stream>>>(big_u, w2, fc2_b + i * CDIM, h,
                                                        h, M, CDIM, MLPD);
  }

  ln_kernel<<<BATCH, 64, 0, stream>>>(h, cls0, norm_g, norm_b, BATCH, (size_t)ncur * CDIM, CDIM);
  gemm_f32<<<dim3(2, 1), 256, 0, stream>>>(cls0, head_w, head_b, out, BATCH, NCLS, CDIM);
}

// Round 4
// 2839.473 us; speedup vs baseline: 5.0114x; 1.1685x over previous
//
#include <hip/hip_runtime.h>
#include <hip/hip_bf16.h>
#include <math.h>

// ---------------- model constants ----------------
#define BATCH 64
#define CDIM 384
#define NHEADS 6
#define HD 64
#define MLPD 1536
#define NLAYERS 12
#define NPATCH 196
#define NTOK0 197
#define NCLS 100

typedef unsigned short ushortT;
typedef __attribute__((ext_vector_type(8))) short short8v;
typedef __attribute__((ext_vector_type(4))) float float4v;

// ---------------- bf16 helpers ----------------
__device__ inline ushortT f2b(float f) {
  union { float f; unsigned u; } x; x.f = f;
  unsigned r = x.u + 0x7fffu + ((x.u >> 16) & 1u);
  return (ushortT)(r >> 16);
}
__device__ inline float b2f(ushortT u) {
  union { unsigned u; float f; } x; x.u = ((unsigned)u) << 16;
  return x.f;
}

// ---------------- wave helpers ----------------
__device__ inline float wave_sum(float v) {
  #pragma unroll
  for (int o = 32; o > 0; o >>= 1) v += __shfl_xor(v, o);
  return v;
}

// ---------------- im2col: x[B,3,224,224] -> P[B*196, 768] bf16 ----------------
__global__ __launch_bounds__(256) void im2col_bf16(const float* __restrict__ x, ushortT* __restrict__ P) {
  int i = blockIdx.x * 256 + threadIdx.x;
  const int total = BATCH * NPATCH * 768;
  if (i >= total) return;
  int k = i % 768;
  int row = i / 768;
  int c = k >> 8;
  int r = k & 255;
  int py = r >> 4, px = r & 15;
  int b = row / NPATCH;
  int p = row % NPATCH;
  int gy = p / 14, gx = p % 14;
  P[i] = f2b(x[(((size_t)b * 3 + c) * 224 + gy * 16 + py) * 224 + gx * 16 + px]);
}

// ---------------- assemble: h[b,0]=cls+pos0; h[b,1+p]=patchout+pos (f32) ----------------
__global__ __launch_bounds__(256) void assemble_kernel(const float* __restrict__ patchout,
                                                       const float* __restrict__ cls_tok,
                                                       const float* __restrict__ pos,
                                                       float* __restrict__ h) {
  int i = blockIdx.x * 256 + threadIdx.x;
  const int total = BATCH * NTOK0 * CDIM;
  if (i >= total) return;
  int c = i % CDIM;
  int n = (i / CDIM) % NTOK0;
  int b = i / (CDIM * NTOK0);
  float v = (n == 0) ? cls_tok[c] : patchout[((size_t)b * NPATCH + (n - 1)) * CDIM + c];
  h[i] = v + pos[n * CDIM + c];
}

// ---------------- weight transpose + bf16 convert: W[K][N] f32 -> Wt[N][K] bf16 ----------------
__global__ __launch_bounds__(256) void wtrans_layer(const float* __restrict__ qkv_w, const float* __restrict__ proj_w,
                                                    const float* __restrict__ fc1_w, const float* __restrict__ fc2_w,
                                                    ushortT* __restrict__ wq, ushortT* __restrict__ wp,
                                                    ushortT* __restrict__ w1, ushortT* __restrict__ w2) {
  int id = blockIdx.x;
  const float* W; ushortT* O; int K, N, t;
  if (id < 432)       { W = qkv_w; O = wq; K = 384;  N = 1152; t = id; }
  else if (id < 576)  { W = proj_w; O = wp; K = 384; N = 384;  t = id - 432; }
  else if (id < 1152) { W = fc1_w; O = w1; K = 384;  N = 1536; t = id - 576; }
  else                { W = fc2_w; O = w2; K = 1536; N = 384;  t = id - 1152; }
  int tilesK = K >> 5;
  int k0 = (t % tilesK) << 5, n0 = (t / tilesK) << 5;
  __shared__ float tile[32][33];
  int tx = threadIdx.x & 31, ty = threadIdx.x >> 5;
  #pragma unroll
  for (int i = 0; i < 4; ++i)
    tile[ty + 8 * i][tx] = W[(size_t)(k0 + ty + 8 * i) * N + n0 + tx];
  __syncthreads();
  #pragma unroll
  for (int i = 0; i < 4; ++i)
    O[(size_t)(n0 + ty + 8 * i) * K + k0 + tx] = f2b(tile[tx][ty + 8 * i]);
}

// single matrix version (patch embed weights)
__global__ __launch_bounds__(256) void wtrans_one(const float* __restrict__ W, ushortT* __restrict__ O, int K, int N) {
  int t = blockIdx.x;
  int tilesK = K >> 5;
  int k0 = (t % tilesK) << 5, n0 = (t / tilesK) << 5;
  __shared__ float tile[32][33];
  int tx = threadIdx.x & 31, ty = threadIdx.x >> 5;
  #pragma unroll
  for (int i = 0; i < 4; ++i)
    tile[ty + 8 * i][tx] = W[(size_t)(k0 + ty + 8 * i) * N + n0 + tx];
  __syncthreads();
  #pragma unroll
  for (int i = 0; i < 4; ++i)
    O[(size_t)(n0 + ty + 8 * i) * K + k0 + tx] = f2b(tile[tx][ty + 8 * i]);
}

// ---------------- MFMA bf16 GEMM: out = act(A@Wt^T + bias) [+ res] ----------------
template<int ACT, int RES, int OBF>
__global__ __launch_bounds__(256) void gemm_mfma(const ushortT* __restrict__ A, const ushortT* __restrict__ Wt,
                                                 const float* __restrict__ bias, const float* __restrict__ res,
                                                 void* __restrict__ outp, int M, int N, int K) {
  __shared__ __align__(16) ushortT As[128][40];
  __shared__ __align__(16) ushortT Bs[128][40];
  const int tid = threadIdx.x;
  const int lane = tid & 63, wave = tid >> 6;
  const int wr = wave >> 1, wc = wave & 1;
  const int bm = blockIdx.y * 128, bn = blockIdx.x * 128;
  float4v acc[4][4] = {};

  const int srow = tid >> 1, sc = (tid & 1) * 16;
  const ushortT* Arow = A + (size_t)(bm + srow) * K + sc;
  const ushortT* Brow = Wt + (size_t)(bn + srow) * K + sc;
  const bool aval = (bm + srow) < M;

  for (int k0 = 0; k0 < K; k0 += 32) {
    uint4 a0 = make_uint4(0u, 0u, 0u, 0u), a1 = make_uint4(0u, 0u, 0u, 0u);
    if (aval) {
      a0 = *(const uint4*)(Arow + k0);
      a1 = *(const uint4*)(Arow + k0 + 8);
    }
    uint4 b0 = *(const uint4*)(Brow + k0);
    uint4 b1 = *(const uint4*)(Brow + k0 + 8);
    __syncthreads();
    *(uint4*)&As[srow][sc] = a0;
    *(uint4*)&As[srow][sc + 8] = a1;
    *(uint4*)&Bs[srow][sc] = b0;
    *(uint4*)&Bs[srow][sc + 8] = b1;
    __syncthreads();
    short8v af[4], bf[4];
    #pragma unroll
    for (int i = 0; i < 4; ++i) {
      af[i] = *(const short8v*)&As[wr * 64 + i * 16 + (lane & 15)][(lane >> 4) * 8];
      bf[i] = *(const short8v*)&Bs[wc * 64 + i * 16 + (lane & 15)][(lane >> 4) * 8];
    }
    #pragma unroll
    for (int i = 0; i < 4; ++i)
      #pragma unroll
      for (int j = 0; j < 4; ++j)
        acc[i][j] = __builtin_amdgcn_mfma_f32_16x16x32_bf16(af[i], bf[j], acc[i][j], 0, 0, 0);
  }

  const int c0 = lane & 15;
  const int r4 = (lane >> 4) * 4;
  #pragma unroll
  for (int i = 0; i < 4; ++i) {
    #pragma unroll
    for (int j = 0; j < 4; ++j) {
      const int col = bn + wc * 64 + j * 16 + c0;
      #pragma unroll
      for (int q = 0; q < 4; ++q) {
        const int row = bm + wr * 64 + i * 16 + r4 + q;
        if (row < M) {
          float v = acc[i][j][q] + bias[col];
          if (ACT == 1) v = 0.5f * v * (1.0f + erff(v * 0.70710678118654752f));
          if (RES) v += res[(size_t)row * N + col];
          if (OBF) ((ushortT*)outp)[(size_t)row * N + col] = f2b(v);
          else     ((float*)outp)[(size_t)row * N + col] = v;
        }
      }
    }
  }
}

// ---------------- layernorm f32 -> bf16 (4 rows per 256-thread block) ----------------
__global__ __launch_bounds__(256) void ln_bf16(const float* __restrict__ in, ushortT* __restrict__ out,
                                               const float* __restrict__ g, const float* __restrict__ bb,
                                               int rows) {
  const int r = blockIdx.x * 4 + (threadIdx.x >> 6);
  if (r >= rows) return;
  const int t = threadIdx.x & 63;
  const float* xr = in + (size_t)r * CDIM;
  ushortT* orow = out + (size_t)r * CDIM;
  float v[6];
  float s = 0.f;
  #pragma unroll
  for (int i = 0; i < 6; ++i) { v[i] = xr[i * 64 + t]; s += v[i]; }
  s = wave_sum(s);
  float mean = s * (1.0f / CDIM);
  float q = 0.f;
  #pragma unroll
  for (int i = 0; i < 6; ++i) { float d = v[i] - mean; q += d * d; }
  q = wave_sum(q);
  float rstd = rsqrtf(q * (1.0f / CDIM) + 1e-6f);
  #pragma unroll
  for (int i = 0; i < 6; ++i) {
    int c = i * 64 + t;
    orow[c] = f2b((v[i] - mean) * rstd * g[c] + bb[c]);
  }
}

// ---------------- layernorm f32->f32 ----------------
__global__ __launch_bounds__(64) void ln_kernel(const float* __restrict__ in, float* __restrict__ out,
                                                const float* __restrict__ g, const float* __restrict__ bb,
                                                int rows, size_t in_stride, size_t out_stride) {
  int r = blockIdx.x;
  if (r >= rows) return;
  const float* xr = in + (size_t)r * in_stride;
  float* orow = out + (size_t)r * out_stride;
  int t = threadIdx.x;
  float v[6];
  float s = 0.f;
  #pragma unroll
  for (int i = 0; i < 6; ++i) { v[i] = xr[i * 64 + t]; s += v[i]; }
  s = wave_sum(s);
  float mean = s * (1.0f / CDIM);
  float q = 0.f;
  #pragma unroll
  for (int i = 0; i < 6; ++i) { float d = v[i] - mean; q += d * d; }
  q = wave_sum(q);
  float rstd = rsqrtf(q * (1.0f / CDIM) + 1e-6f);
  #pragma unroll
  for (int i = 0; i < 6; ++i) {
    int c = i * 64 + t;
    orow[c] = (v[i] - mean) * rstd * g[c] + bb[c];
  }
}

// ---------------- attention v3: MFMA ----------------
template<int KS>
__global__ __launch_bounds__(256) void attn3(const ushortT* __restrict__ qkv, ushortT* __restrict__ attnout,
                                             float* __restrict__ cls_attn, int N) {
  constexpr int NT = 2 * KS;
  constexpr int KT = 32 * KS;
  const int h = blockIdx.y, b = blockIdx.z;
  const int rb = blockIdx.x * 64;
  const int tid = threadIdx.x;
  const int w = tid >> 6, l = tid & 63;
  const int c = l & 15, g = l >> 4;

  __shared__ __align__(16) ushortT Vt[64][232];      // V^T: [dim][token]
  __shared__ __align__(16) ushortT Ps[4][16][232];   // per-wave P (bf16), rows=q, cols=k

  const ushortT* bq = qkv + (size_t)(b * N) * 1152 + (size_t)h * 64;

  // ---- stage V transposed ----
  {
    const int vr = tid >> 3, vc = (tid & 7) * 8;
    for (int p = 0; p < KT; p += 32) {
      const int m = vr + p;
      if (m < N) {
        short8v v8 = *(const short8v*)(bq + (size_t)m * 1152 + 768 + vc);
        #pragma unroll
        for (int j = 0; j < 8; ++j) Vt[vc + j][m] = (ushortT)v8[j];
      } else if (m < KT) {
        #pragma unroll
        for (int j = 0; j < 8; ++j) Vt[vc + j][m] = 0;
      }
    }
  }
  __syncthreads();

  // ---- Q A-fragments from global ----
  short8v qf0, qf1;
  {
    int row = rb + 16 * w + c; if (row >= N) row = N - 1;
    const ushortT* qrow = bq + (size_t)row * 1152;
    qf0 = *(const short8v*)(qrow + g * 8);
    qf1 = *(const short8v*)(qrow + 32 + g * 8);
  }

  // ---- S = Q@K^T ----
  float4v sc[NT];
  #pragma unroll
  for (int kt = 0; kt < NT; ++kt) {
    int krow = 16 * kt + c; if (krow >= N) krow = N - 1;
    const ushortT* kr = bq + (size_t)krow * 1152 + 384;
    short8v b0 = *(const short8v*)(kr + g * 8);
    short8v b1 = *(const short8v*)(kr + 32 + g * 8);
    float4v a = {};
    a = __builtin_amdgcn_mfma_f32_16x16x32_bf16(qf0, b0, a, 0, 0, 0);
    a = __builtin_amdgcn_mfma_f32_16x16x32_bf16(qf1, b1, a, 0, 0, 0);
    sc[kt] = a;
  }

  // ---- softmax ----
  float m4[4] = {-INFINITY, -INFINITY, -INFINITY, -INFINITY};
  #pragma unroll
  for (int kt = 0; kt < NT; ++kt) {
    const bool valid = (16 * kt + c) < N;
    #pragma unroll
    for (int q = 0; q < 4; ++q) {
      float s = valid ? sc[kt][q] * 0.125f : -INFINITY;
      sc[kt][q] = s;
      m4[q] = fmaxf(m4[q], s);
    }
  }
  #pragma unroll
  for (int q = 0; q < 4; ++q) {
    #pragma unroll
    for (int o = 1; o <= 8; o <<= 1) m4[q] = fmaxf(m4[q], __shfl_xor(m4[q], o));
  }
  float sum4[4] = {0.f, 0.f, 0.f, 0.f};
  #pragma unroll
  for (int kt = 0; kt < NT; ++kt) {
    #pragma unroll
    for (int q = 0; q < 4; ++q) {
      float e = __expf(sc[kt][q] - m4[q]);
      sc[kt][q] = e;
      sum4[q] += e;
    }
  }
  #pragma unroll
  for (int q = 0; q < 4; ++q) {
    #pragma unroll
    for (int o = 1; o <= 8; o <<= 1) sum4[q] += __shfl_xor(sum4[q], o);
  }
  float inv4[4];
  #pragma unroll
  for (int q = 0; q < 4; ++q) inv4[q] = 1.0f / sum4[q];

  // ---- write P ----
  #pragma unroll
  for (int kt = 0; kt < NT; ++kt) {
    #pragma unroll
    for (int q = 0; q < 4; ++q) Ps[w][4 * g + q][16 * kt + c] = f2b(sc[kt][q]);
  }

  // ---- CLS attention probs ----
  if (rb == 0 && w == 0 && g == 0) {
    const float inv0 = inv4[0];
    #pragma unroll
    for (int kt = 0; kt < NT; ++kt) {
      const int col = 16 * kt + c;
      if (col >= 1 && col < N)
        cls_attn[((size_t)b * NHEADS + h) * (N - 1) + (col - 1)] = sc[kt][0] * inv0;
    }
  }

  // ---- O = P @ V ----
  float4v oacc[4] = {};
  #pragma unroll
  for (int s2 = 0; s2 < KS; ++s2) {
    short8v pa = *(const short8v*)&Ps[w][c][32 * s2 + 8 * g];
    #pragma unroll
    for (int nt = 0; nt < 4; ++nt) {
      short8v vb = *(const short8v*)&Vt[16 * nt + c][32 * s2 + 8 * g];
      oacc[nt] = __builtin_amdgcn_mfma_f32_16x16x32_bf16(pa, vb, oacc[nt], 0, 0, 0);
    }
  }

  // ---- epilogue ----
  #pragma unroll
  for (int nt = 0; nt < 4; ++nt) {
    #pragma unroll
    for (int q = 0; q < 4; ++q) {
      const int row = rb + 16 * w + 4 * g + q;
      if (row < N)
        attnout[((size_t)(b * N + row)) * CDIM + h * 64 + 16 * nt + c] = f2b(oacc[nt][q] * inv4[q]);
    }
  }
}

// ---------------- fused clsscore + rank top-k ----------------
// one block per batch; thread j owns token j. Produces idx[b][r] for r<keep in
// exact descending (tie -> smaller index) order, matching jax.lax.top_k.
__global__ __launch_bounds__(256) void topk_rank(const float* __restrict__ cls_attn, int* __restrict__ idx,
                                                 int Nm1, int Kkeep) {
  const int b = blockIdx.x;
  const int t = threadIdx.x;
  __shared__ float s_sc[224];
  if (t < Nm1) {
    const float* ca = cls_attn + (size_t)b * NHEADS * Nm1 + t;
    float s = 0.f;
    #pragma unroll
    for (int h = 0; h < NHEADS; ++h) s += ca[h * Nm1];
    s_sc[t] = s * (1.0f / NHEADS);
  }
  __syncthreads();
  if (t < Nm1) {
    const float mys = s_sc[t];
    int r = 0;
    for (int i = 0; i < Nm1; ++i) {
      float si = s_sc[i];
      r += (si > mys || (si == mys && i < t)) ? 1 : 0;
    }
    if (r < Kkeep) idx[b * Kkeep + r] = t;
  }
}

// ---------------- gather pruned tokens (f32 h -> f32 hdst) ----------------
__global__ __launch_bounds__(256) void gather_kernel(const float* __restrict__ h, const int* __restrict__ idx,
                                                     float* __restrict__ outb, int N, int Kkeep) {
  size_t total = (size_t)BATCH * (1 + Kkeep) * CDIM;
  size_t i = (size_t)blockIdx.x * 256 + threadIdx.x;
  if (i >= total) return;
  int c = (int)(i % CDIM);
  size_t r = i / CDIM;
  int n = (int)(r % (1 + Kkeep));
  int b = (int)(r / (1 + Kkeep));
  int src = (n == 0) ? 0 : 1 + idx[b * Kkeep + (n - 1)];
  outb[i] = h[((size_t)b * N + src) * CDIM + c];
}

// ---------------- small f32 GEMM (head only) ----------------
__global__ __launch_bounds__(256) void gemm_f32(const float* __restrict__ A, const float* __restrict__ W,
                                                const float* __restrict__ bias, float* __restrict__ out,
                                                int M, int N, int K) {
  __shared__ __align__(16) float As[16][64];
  __shared__ __align__(16) float Ws[16][64];
  const int tid = threadIdx.x;
  const int tx = tid & 15, ty = tid >> 4;
  const int bm = blockIdx.y * 64, bn = blockIdx.x * 64;
  float acc[4][4] = {};
  const int ma = tid >> 2;
  const int ka = (tid & 3) << 2;
  const int kw = ty;
  const int nw = tx << 2;
  for (int k0 = 0; k0 < K; k0 += 16) {
    {
      float4 a4 = make_float4(0.f, 0.f, 0.f, 0.f);
      if (bm + ma < M) a4 = *reinterpret_cast<const float4*>(&A[(size_t)(bm + ma) * K + k0 + ka]);
      As[ka + 0][ma] = a4.x; As[ka + 1][ma] = a4.y; As[ka + 2][ma] = a4.z; As[ka + 3][ma] = a4.w;
    }
    {
      const int gn = bn + nw;
      const float* wp = &W[(size_t)(k0 + kw) * N + gn];
      #pragma unroll
      for (int j = 0; j < 4; ++j) Ws[kw][nw + j] = (gn + j < N) ? wp[j] : 0.f;
    }
    __syncthreads();
    #pragma unroll
    for (int kk = 0; kk < 16; ++kk) {
      float4 a = *reinterpret_cast<const float4*>(&As[kk][ty << 2]);
      float4 w = *reinterpret_cast<const float4*>(&Ws[kk][tx << 2]);
      float av[4] = {a.x, a.y, a.z, a.w};
      float wv[4] = {w.x, w.y, w.z, w.w};
      #pragma unroll
      for (int i = 0; i < 4; ++i)
        #pragma unroll
        for (int j = 0; j < 4; ++j)
          acc[i][j] = fmaf(av[i], wv[j], acc[i][j]);
    }
    __syncthreads();
  }
  #pragma unroll
  for (int i = 0; i < 4; ++i) {
    int r = bm + (ty << 2) + i;
    if (r >= M) continue;
    #pragma unroll
    for (int j = 0; j < 4; ++j) {
      int cidx = bn + (tx << 2) + j;
      if (cidx >= N) continue;
      out[(size_t)r * N + cidx] = acc[i][j] + bias[cidx];
    }
  }
}

// ---------------- host launch ----------------
extern "C" void kernel_launch(void* const* d_in, const int* in_sizes, int n_in,
                              void* d_out, int out_size, void* d_ws, size_t ws_size,
                              hipStream_t stream) {
  const float* x        = (const float*)d_in[0];
  const float* patch_w  = (const float*)d_in[1];
  const float* patch_b  = (const float*)d_in[2];
  const float* cls_tok  = (const float*)d_in[3];
  const float* pos      = (const float*)d_in[4];
  const float* ln1_g    = (const float*)d_in[5];
  const float* ln1_b    = (const float*)d_in[6];
  const float* qkv_w    = (const float*)d_in[7];
  const float* qkv_b    = (const float*)d_in[8];
  const float* proj_w   = (const float*)d_in[9];
  const float* proj_b   = (const float*)d_in[10];
  const float* ln2_g    = (const float*)d_in[11];
  const float* ln2_b    = (const float*)d_in[12];
  const float* fc1_w    = (const float*)d_in[13];
  const float* fc1_b    = (const float*)d_in[14];
  const float* fc2_w    = (const float*)d_in[15];
  const float* fc2_b    = (const float*)d_in[16];
  const float* norm_g   = (const float*)d_in[17];
  const float* norm_b   = (const float*)d_in[18];
  const float* head_w   = (const float*)d_in[19];
  const float* head_b   = (const float*)d_in[20];
  float* out = (float*)d_out;

  float* ws = (float*)d_ws;
  // ---- workspace layout (float offsets) ----
  float* hA       = ws;                          // [B,197,C] f32
  float* big      = ws + 4841472;                // qkv bf16 (7.26M f) / fc1 hidden bf16 (9.68M f) / im2col / patchout
  ushortT* big_u  = (ushortT*)big;
  float* patchout = big + 4816896;               // f32, patch-embed only
  float* hB       = ws + 14524416;               // [B,<=197,C] f32 ping-pong (gap after fc1-hidden end)
  ushortT* lnb_u  = (ushortT*)(ws + 19365888);
  ushortT* attn_u = (ushortT*)(ws + 21786624);
  ushortT* wbuf_u = (ushortT*)(ws + 24207360);
  float* cls_attn = ws + 25092096;
  int*   idxbuf   = (int*)(ws + 25179904);
  float* cls0     = ws + 25191168;

  ushortT* wq = wbuf_u;
  ushortT* wp = wbuf_u + 442368;
  ushortT* w1 = wbuf_u + 589824;
  ushortT* w2 = wbuf_u + 1179648;

  // ---- patch embed ----
  {
    int total = BATCH * NPATCH * 768;
    im2col_bf16<<<(total + 255) / 256, 256, 0, stream>>>(x, big_u);
    wtrans_one<<<288, 256, 0, stream>>>(patch_w, wbuf_u, 768, CDIM);
    gemm_mfma<0, 0, 0><<<dim3(3, 98), 256, 0, stream>>>(big_u, wbuf_u, patch_b, nullptr, patchout,
                                                        BATCH * NPATCH, CDIM, 768);
    int tot2 = BATCH * NTOK0 * CDIM;
    assemble_kernel<<<(tot2 + 255) / 256, 256, 0, stream>>>(patchout, cls_tok, pos, hA);
  }

  float* h = hA;
  float* hOther = hB;
  int ncur = NTOK0;
  for (int i = 0; i < NLAYERS; ++i) {
    int M = BATCH * ncur;
    int gy = (M + 127) / 128;
    wtrans_layer<<<1728, 256, 0, stream>>>(qkv_w + (size_t)i * CDIM * 3 * CDIM,
                                           proj_w + (size_t)i * CDIM * CDIM,
                                           fc1_w + (size_t)i * CDIM * MLPD,
                                           fc2_w + (size_t)i * MLPD * CDIM,
                                           wq, wp, w1, w2);
    ln_bf16<<<(M + 3) / 4, 256, 0, stream>>>(h, lnb_u, ln1_g + i * CDIM, ln1_b + i * CDIM, M);
    gemm_mfma<0, 0, 1><<<dim3(9, gy), 256, 0, stream>>>(lnb_u, wq, qkv_b + i * 3 * CDIM, nullptr,
                                                        big_u, M, 3 * CDIM, CDIM);
    // attention (MFMA)
    {
      dim3 g((ncur + 63) / 64, NHEADS, BATCH);
      int ks = (ncur + 31) / 32;
      if (ks == 7)      attn3<7><<<g, 256, 0, stream>>>(big_u, attn_u, cls_attn, ncur);
      else if (ks == 6) attn3<6><<<g, 256, 0, stream>>>(big_u, attn_u, cls_attn, ncur);
      else if (ks == 5) attn3<5><<<g, 256, 0, stream>>>(big_u, attn_u, cls_attn, ncur);
      else              attn3<4><<<g, 256, 0, stream>>>(big_u, attn_u, cls_attn, ncur);
    }
    gemm_mfma<0, 1, 0><<<dim3(3, gy), 256, 0, stream>>>(attn_u, wp, proj_b + i * CDIM, h,
                                                        h, M, CDIM, CDIM);
    if (i == 2 || i == 4 || i == 6) {
      int keep = (i == 2) ? 176 : (i == 4) ? 149 : 119;
      int Nm1 = ncur - 1;
      topk_rank<<<BATCH, 256, 0, stream>>>(cls_attn, idxbuf, Nm1, keep);
      int newN = 1 + keep;
      size_t gtot = (size_t)BATCH * newN * CDIM;
      gather_kernel<<<(int)((gtot + 255) / 256), 256, 0, stream>>>(h, idxbuf, hOther, ncur, keep);
      float* tmp = h; h = hOther; hOther = tmp;
      ncur = newN;
      M = BATCH * ncur;
      gy = (M + 127) / 128;
    }
    ln_bf16<<<(M + 3) / 4, 256, 0, stream>>>(h, lnb_u, ln2_g + i * CDIM, ln2_b + i * CDIM, M);
    gemm_mfma<1, 0, 1><<<dim3(12, gy), 256, 0, stream>>>(lnb_u, w1, fc1_b + i * MLPD, nullptr,
                                                         big_u, M, MLPD, CDIM);
    gemm_mfma<0, 1, 0><<<dim3(3, gy), 256, 0, stream>>>(big_u, w2, fc2_b + i * CDIM, h,
                                                        h, M, CDIM, MLPD);
  }

  ln_kernel<<<BATCH, 64, 0, stream>>>(h, cls0, norm_g, norm_b, BATCH, (size_t)ncur * CDIM, CDIM);
  gemm_f32<<<dim3(2, 1), 256, 0, stream>>>(cls0, head_w, head_b, out, BATCH, NCLS, CDIM);
}

// Round 7
// 2750.619 us; speedup vs baseline: 5.1733x; 1.0323x over previous
//
#include <hip/hip_runtime.h>
#include <hip/hip_bf16.h>
#include <math.h>

// ---------------- model constants ----------------
#define BATCH 64
#define CDIM 384
#define NHEADS 6
#define HD 64
#define MLPD 1536
#define NLAYERS 12
#define NPATCH 196
#define NTOK0 197
#define NCLS 100

typedef unsigned short ushortT;
typedef __attribute__((ext_vector_type(8))) short short8v;
typedef __attribute__((ext_vector_type(4))) float float4v;

// ---------------- bf16 helpers ----------------
__device__ inline ushortT f2b(float f) {
  union { float f; unsigned u; } x; x.f = f;
  unsigned r = x.u + 0x7fffu + ((x.u >> 16) & 1u);
  return (ushortT)(r >> 16);
}
__device__ inline float b2f(ushortT u) {
  union { unsigned u; float f; } x; x.u = ((unsigned)u) << 16;
  return x.f;
}

// async global->LDS, 16B per lane; lds base must be wave-uniform (HW: base + lane*16)
__device__ inline void gload_lds16(const ushortT* g, ushortT* l) {
  __builtin_amdgcn_global_load_lds((const __attribute__((address_space(1))) void*)g,
                                   (__attribute__((address_space(3))) void*)l, 16, 0, 0);
}

// ---------------- wave helpers ----------------
__device__ inline float wave_sum(float v) {
  #pragma unroll
  for (int o = 32; o > 0; o >>= 1) v += __shfl_xor(v, o);
  return v;
}

// ---------------- im2col: x[B,3,224,224] -> P[B*196, 768] bf16 ----------------
__global__ __launch_bounds__(256) void im2col_bf16(const float* __restrict__ x, ushortT* __restrict__ P) {
  int i = blockIdx.x * 256 + threadIdx.x;
  const int total = BATCH * NPATCH * 768;
  if (i >= total) return;
  int k = i % 768;
  int row = i / 768;
  int c = k >> 8;
  int r = k & 255;
  int py = r >> 4, px = r & 15;
  int b = row / NPATCH;
  int p = row % NPATCH;
  int gy = p / 14, gx = p % 14;
  P[i] = f2b(x[(((size_t)b * 3 + c) * 224 + gy * 16 + py) * 224 + gx * 16 + px]);
}

// ---------------- assemble ----------------
__global__ __launch_bounds__(256) void assemble_kernel(const float* __restrict__ patchout,
                                                       const float* __restrict__ cls_tok,
                                                       const float* __restrict__ pos,
                                                       float* __restrict__ h) {
  int i = blockIdx.x * 256 + threadIdx.x;
  const int total = BATCH * NTOK0 * CDIM;
  if (i >= total) return;
  int c = i % CDIM;
  int n = (i / CDIM) % NTOK0;
  int b = i / (CDIM * NTOK0);
  float v = (n == 0) ? cls_tok[c] : patchout[((size_t)b * NPATCH + (n - 1)) * CDIM + c];
  h[i] = v + pos[n * CDIM + c];
}

// ---------------- weight transpose + bf16 convert ----------------
__global__ __launch_bounds__(256) void wtrans_layer(const float* __restrict__ qkv_w, const float* __restrict__ proj_w,
                                                    const float* __restrict__ fc1_w, const float* __restrict__ fc2_w,
                                                    ushortT* __restrict__ wq, ushortT* __restrict__ wp,
                                                    ushortT* __restrict__ w1, ushortT* __restrict__ w2) {
  int id = blockIdx.x;
  const float* W; ushortT* O; int K, N, t;
  if (id < 432)       { W = qkv_w; O = wq; K = 384;  N = 1152; t = id; }
  else if (id < 576)  { W = proj_w; O = wp; K = 384; N = 384;  t = id - 432; }
  else if (id < 1152) { W = fc1_w; O = w1; K = 384;  N = 1536; t = id - 576; }
  else                { W = fc2_w; O = w2; K = 1536; N = 384;  t = id - 1152; }
  int tilesK = K >> 5;
  int k0 = (t % tilesK) << 5, n0 = (t / tilesK) << 5;
  __shared__ float tile[32][33];
  int tx = threadIdx.x & 31, ty = threadIdx.x >> 5;
  #pragma unroll
  for (int i = 0; i < 4; ++i)
    tile[ty + 8 * i][tx] = W[(size_t)(k0 + ty + 8 * i) * N + n0 + tx];
  __syncthreads();
  #pragma unroll
  for (int i = 0; i < 4; ++i)
    O[(size_t)(n0 + ty + 8 * i) * K + k0 + tx] = f2b(tile[tx][ty + 8 * i]);
}

// single matrix version (patch embed weights)
__global__ __launch_bounds__(256) void wtrans_one(const float* __restrict__ W, ushortT* __restrict__ O, int K, int N) {
  int t = blockIdx.x;
  int tilesK = K >> 5;
  int k0 = (t % tilesK) << 5, n0 = (t / tilesK) << 5;
  __shared__ float tile[32][33];
  int tx = threadIdx.x & 31, ty = threadIdx.x >> 5;
  #pragma unroll
  for (int i = 0; i < 4; ++i)
    tile[ty + 8 * i][tx] = W[(size_t)(k0 + ty + 8 * i) * N + n0 + tx];
  __syncthreads();
  #pragma unroll
  for (int i = 0; i < 4; ++i)
    O[(size_t)(n0 + ty + 8 * i) * K + k0 + tx] = f2b(tile[tx][ty + 8 * i]);
}

// ---------------- MFMA bf16 GEMM (global_load_lds staging, linear LDS) ----------------
// out = act(A@Wt^T + bias) [+ res]; A:[M][K] bf16, Wt:[N][K] bf16. N%128==0.
template<int ACT, int RES, int OBF>
__global__ __launch_bounds__(256) void gemm_mfma(const ushortT* __restrict__ A, const ushortT* __restrict__ Wt,
                                                 const float* __restrict__ bias, const float* __restrict__ res,
                                                 void* __restrict__ outp, int M, int N, int K) {
  // linear tiles [128][32] bf16 (64B row stride): frag ds_read_b128 per wave
  // covers a contiguous 1KB region -> conflict-free.
  __shared__ __align__(16) ushortT Asl[128 * 32];
  __shared__ __align__(16) ushortT Bsl[128 * 32];
  const int tid = threadIdx.x;
  const int lane = tid & 63, wave = tid >> 6;
  const int wr = wave >> 1, wc = wave & 1;
  const int bm = blockIdx.y * 128, bn = blockIdx.x * 128;
  float4v acc[4][4] = {};

  // staging map: LDS elem off = j*2048 + wave*512 + lane*8
  //   -> row = j*64 + wave*16 + lane/4, col = (lane&3)*8
  const int srow = wave * 16 + (lane >> 2);
  const int scol = (lane & 3) * 8;
  const ushortT* ag0 = A + (size_t)(bm + srow) * K + scol;        // rows bm..bm+63
  const ushortT* ag1 = A + (size_t)(bm + 64 + srow) * K + scol;   // rows bm+64..
  const ushortT* bg0 = Wt + (size_t)(bn + srow) * K + scol;
  const ushortT* bg1 = Wt + (size_t)(bn + 64 + srow) * K + scol;
  ushortT* ldsA0 = &Asl[wave * 512];
  ushortT* ldsA1 = &Asl[2048 + wave * 512];
  ushortT* ldsB0 = &Bsl[wave * 512];
  ushortT* ldsB1 = &Bsl[2048 + wave * 512];

  const int fr = lane & 15, g8 = (lane >> 4) * 8;

  for (int k0 = 0; k0 < K; k0 += 32) {
    gload_lds16(ag0 + k0, ldsA0);
    gload_lds16(ag1 + k0, ldsA1);
    gload_lds16(bg0 + k0, ldsB0);
    gload_lds16(bg1 + k0, ldsB1);
    __syncthreads();  // vmcnt(0) drain: staged tiles visible
    short8v af[4], bf[4];
    #pragma unroll
    for (int i = 0; i < 4; ++i) {
      af[i] = *(const short8v*)&Asl[(wr * 64 + i * 16 + fr) * 32 + g8];
      bf[i] = *(const short8v*)&Bsl[(wc * 64 + i * 16 + fr) * 32 + g8];
    }
    #pragma unroll
    for (int i = 0; i < 4; ++i)
      #pragma unroll
      for (int j = 0; j < 4; ++j)
        acc[i][j] = __builtin_amdgcn_mfma_f32_16x16x32_bf16(af[i], bf[j], acc[i][j], 0, 0, 0);
    __syncthreads();  // all frags read before next-tile overwrite
  }

  const int c0 = lane & 15;
  const int r4 = (lane >> 4) * 4;
  #pragma unroll
  for (int i = 0; i < 4; ++i) {
    #pragma unroll
    for (int j = 0; j < 4; ++j) {
      const int col = bn + wc * 64 + j * 16 + c0;
      #pragma unroll
      for (int q = 0; q < 4; ++q) {
        const int row = bm + wr * 64 + i * 16 + r4 + q;
        if (row < M) {
          float v = acc[i][j][q] + bias[col];
          if (ACT == 1) v = 0.5f * v * (1.0f + erff(v * 0.70710678118654752f));
          if (RES) v += res[(size_t)row * N + col];
          if (OBF) ((ushortT*)outp)[(size_t)row * N + col] = f2b(v);
          else     ((float*)outp)[(size_t)row * N + col] = v;
        }
      }
    }
  }
}

// ---------------- layernorm f32 -> bf16 (4 rows per 256-thread block) ----------------
__global__ __launch_bounds__(256) void ln_bf16(const float* __restrict__ in, ushortT* __restrict__ out,
                                               const float* __restrict__ g, const float* __restrict__ bb,
                                               int rows) {
  const int r = blockIdx.x * 4 + (threadIdx.x >> 6);
  if (r >= rows) return;
  const int t = threadIdx.x & 63;
  const float* xr = in + (size_t)r * CDIM;
  ushortT* orow = out + (size_t)r * CDIM;
  float v[6];
  float s = 0.f;
  #pragma unroll
  for (int i = 0; i < 6; ++i) { v[i] = xr[i * 64 + t]; s += v[i]; }
  s = wave_sum(s);
  float mean = s * (1.0f / CDIM);
  float q = 0.f;
  #pragma unroll
  for (int i = 0; i < 6; ++i) { float d = v[i] - mean; q += d * d; }
  q = wave_sum(q);
  float rstd = rsqrtf(q * (1.0f / CDIM) + 1e-6f);
  #pragma unroll
  for (int i = 0; i < 6; ++i) {
    int c = i * 64 + t;
    orow[c] = f2b((v[i] - mean) * rstd * g[c] + bb[c]);
  }
}

// ---------------- layernorm f32->f32 ----------------
__global__ __launch_bounds__(64) void ln_kernel(const float* __restrict__ in, float* __restrict__ out,
                                                const float* __restrict__ g, const float* __restrict__ bb,
                                                int rows, size_t in_stride, size_t out_stride) {
  int r = blockIdx.x;
  if (r >= rows) return;
  const float* xr = in + (size_t)r * in_stride;
  float* orow = out + (size_t)r * out_stride;
  int t = threadIdx.x;
  float v[6];
  float s = 0.f;
  #pragma unroll
  for (int i = 0; i < 6; ++i) { v[i] = xr[i * 64 + t]; s += v[i]; }
  s = wave_sum(s);
  float mean = s * (1.0f / CDIM);
  float q = 0.f;
  #pragma unroll
  for (int i = 0; i < 6; ++i) { float d = v[i] - mean; q += d * d; }
  q = wave_sum(q);
  float rstd = rsqrtf(q * (1.0f / CDIM) + 1e-6f);
  #pragma unroll
  for (int i = 0; i < 6; ++i) {
    int c = i * 64 + t;
    orow[c] = (v[i] - mean) * rstd * g[c] + bb[c];
  }
}

// ---------------- attention v3: MFMA ----------------
template<int KS>
__global__ __launch_bounds__(256) void attn3(const ushortT* __restrict__ qkv, ushortT* __restrict__ attnout,
                                             float* __restrict__ cls_attn, int N) {
  constexpr int NT = 2 * KS;
  constexpr int KT = 32 * KS;
  const int h = blockIdx.y, b = blockIdx.z;
  const int rb = blockIdx.x * 64;
  const int tid = threadIdx.x;
  const int w = tid >> 6, l = tid & 63;
  const int c = l & 15, g = l >> 4;

  __shared__ __align__(16) ushortT Vt[64][232];      // V^T: [dim][token]
  __shared__ __align__(16) ushortT Ps[4][16][232];   // per-wave P (bf16)

  const ushortT* bq = qkv + (size_t)(b * N) * 1152 + (size_t)h * 64;

  // ---- stage V transposed ----
  {
    const int vr = tid >> 3, vc = (tid & 7) * 8;
    for (int p = 0; p < KT; p += 32) {
      const int m = vr + p;
      if (m < N) {
        short8v v8 = *(const short8v*)(bq + (size_t)m * 1152 + 768 + vc);
        #pragma unroll
        for (int j = 0; j < 8; ++j) Vt[vc + j][m] = (ushortT)v8[j];
      } else if (m < KT) {
        #pragma unroll
        for (int j = 0; j < 8; ++j) Vt[vc + j][m] = 0;
      }
    }
  }
  __syncthreads();

  // ---- Q A-fragments from global ----
  short8v qf0, qf1;
  {
    int row = rb + 16 * w + c; if (row >= N) row = N - 1;
    const ushortT* qrow = bq + (size_t)row * 1152;
    qf0 = *(const short8v*)(qrow + g * 8);
    qf1 = *(const short8v*)(qrow + 32 + g * 8);
  }

  // ---- S = Q@K^T ----
  float4v sc[NT];
  #pragma unroll
  for (int kt = 0; kt < NT; ++kt) {
    int krow = 16 * kt + c; if (krow >= N) krow = N - 1;
    const ushortT* kr = bq + (size_t)krow * 1152 + 384;
    short8v b0 = *(const short8v*)(kr + g * 8);
    short8v b1 = *(const short8v*)(kr + 32 + g * 8);
    float4v a = {};
    a = __builtin_amdgcn_mfma_f32_16x16x32_bf16(qf0, b0, a, 0, 0, 0);
    a = __builtin_amdgcn_mfma_f32_16x16x32_bf16(qf1, b1, a, 0, 0, 0);
    sc[kt] = a;
  }

  // ---- softmax ----
  float m4[4] = {-INFINITY, -INFINITY, -INFINITY, -INFINITY};
  #pragma unroll
  for (int kt = 0; kt < NT; ++kt) {
    const bool valid = (16 * kt + c) < N;
    #pragma unroll
    for (int q = 0; q < 4; ++q) {
      float s = valid ? sc[kt][q] * 0.125f : -INFINITY;
      sc[kt][q] = s;
      m4[q] = fmaxf(m4[q], s);
    }
  }
  #pragma unroll
  for (int q = 0; q < 4; ++q) {
    #pragma unroll
    for (int o = 1; o <= 8; o <<= 1) m4[q] = fmaxf(m4[q], __shfl_xor(m4[q], o));
  }
  float sum4[4] = {0.f, 0.f, 0.f, 0.f};
  #pragma unroll
  for (int kt = 0; kt < NT; ++kt) {
    #pragma unroll
    for (int q = 0; q < 4; ++q) {
      float e = __expf(sc[kt][q] - m4[q]);
      sc[kt][q] = e;
      sum4[q] += e;
    }
  }
  #pragma unroll
  for (int q = 0; q < 4; ++q) {
    #pragma unroll
    for (int o = 1; o <= 8; o <<= 1) sum4[q] += __shfl_xor(sum4[q], o);
  }
  float inv4[4];
  #pragma unroll
  for (int q = 0; q < 4; ++q) inv4[q] = 1.0f / sum4[q];

  // ---- write P ----
  #pragma unroll
  for (int kt = 0; kt < NT; ++kt) {
    #pragma unroll
    for (int q = 0; q < 4; ++q) Ps[w][4 * g + q][16 * kt + c] = f2b(sc[kt][q]);
  }

  // ---- CLS attention probs ----
  if (rb == 0 && w == 0 && g == 0) {
    const float inv0 = inv4[0];
    #pragma unroll
    for (int kt = 0; kt < NT; ++kt) {
      const int col = 16 * kt + c;
      if (col >= 1 && col < N)
        cls_attn[((size_t)b * NHEADS + h) * (N - 1) + (col - 1)] = sc[kt][0] * inv0;
    }
  }

  // ---- O = P @ V ----
  float4v oacc[4] = {};
  #pragma unroll
  for (int s2 = 0; s2 < KS; ++s2) {
    short8v pa = *(const short8v*)&Ps[w][c][32 * s2 + 8 * g];
    #pragma unroll
    for (int nt = 0; nt < 4; ++nt) {
      short8v vb = *(const short8v*)&Vt[16 * nt + c][32 * s2 + 8 * g];
      oacc[nt] = __builtin_amdgcn_mfma_f32_16x16x32_bf16(pa, vb, oacc[nt], 0, 0, 0);
    }
  }

  // ---- epilogue ----
  #pragma unroll
  for (int nt = 0; nt < 4; ++nt) {
    #pragma unroll
    for (int q = 0; q < 4; ++q) {
      const int row = rb + 16 * w + 4 * g + q;
      if (row < N)
        attnout[((size_t)(b * N + row)) * CDIM + h * 64 + 16 * nt + c] = f2b(oacc[nt][q] * inv4[q]);
    }
  }
}

// ---------------- fused clsscore + rank top-k ----------------
__global__ __launch_bounds__(256) void topk_rank(const float* __restrict__ cls_attn, int* __restrict__ idx,
                                                 int Nm1, int Kkeep) {
  const int b = blockIdx.x;
  const int t = threadIdx.x;
  __shared__ float s_sc[224];
  if (t < Nm1) {
    const float* ca = cls_attn + (size_t)b * NHEADS * Nm1 + t;
    float s = 0.f;
    #pragma unroll
    for (int h = 0; h < NHEADS; ++h) s += ca[h * Nm1];
    s_sc[t] = s * (1.0f / NHEADS);
  }
  __syncthreads();
  if (t < Nm1) {
    const float mys = s_sc[t];
    int r = 0;
    for (int i = 0; i < Nm1; ++i) {
      float si = s_sc[i];
      r += (si > mys || (si == mys && i < t)) ? 1 : 0;
    }
    if (r < Kkeep) idx[b * Kkeep + r] = t;
  }
}

// ---------------- gather pruned tokens ----------------
__global__ __launch_bounds__(256) void gather_kernel(const float* __restrict__ h, const int* __restrict__ idx,
                                                     float* __restrict__ outb, int N, int Kkeep) {
  size_t total = (size_t)BATCH * (1 + Kkeep) * CDIM;
  size_t i = (size_t)blockIdx.x * 256 + threadIdx.x;
  if (i >= total) return;
  int c = (int)(i % CDIM);
  size_t r = i / CDIM;
  int n = (int)(r % (1 + Kkeep));
  int b = (int)(r / (1 + Kkeep));
  int src = (n == 0) ? 0 : 1 + idx[b * Kkeep + (n - 1)];
  outb[i] = h[((size_t)b * N + src) * CDIM + c];
}

// ---------------- small f32 GEMM (head only) ----------------
__global__ __launch_bounds__(256) void gemm_f32(const float* __restrict__ A, const float* __restrict__ W,
                                                const float* __restrict__ bias, float* __restrict__ out,
                                                int M, int N, int K) {
  __shared__ __align__(16) float As[16][64];
  __shared__ __align__(16) float Ws[16][64];
  const int tid = threadIdx.x;
  const int tx = tid & 15, ty = tid >> 4;
  const int bm = blockIdx.y * 64, bn = blockIdx.x * 64;
  float acc[4][4] = {};
  const int ma = tid >> 2;
  const int ka = (tid & 3) << 2;
  const int kw = ty;
  const int nw = tx << 2;
  for (int k0 = 0; k0 < K; k0 += 16) {
    {
      float4 a4 = make_float4(0.f, 0.f, 0.f, 0.f);
      if (bm + ma < M) a4 = *reinterpret_cast<const float4*>(&A[(size_t)(bm + ma) * K + k0 + ka]);
      As[ka + 0][ma] = a4.x; As[ka + 1][ma] = a4.y; As[ka + 2][ma] = a4.z; As[ka + 3][ma] = a4.w;
    }
    {
      const int gn = bn + nw;
      const float* wp = &W[(size_t)(k0 + kw) * N + gn];
      #pragma unroll
      for (int j = 0; j < 4; ++j) Ws[kw][nw + j] = (gn + j < N) ? wp[j] : 0.f;
    }
    __syncthreads();
    #pragma unroll
    for (int kk = 0; kk < 16; ++kk) {
      float4 a = *reinterpret_cast<const float4*>(&As[kk][ty << 2]);
      float4 w = *reinterpret_cast<const float4*>(&Ws[kk][tx << 2]);
      float av[4] = {a.x, a.y, a.z, a.w};
      float wv[4] = {w.x, w.y, w.z, w.w};
      #pragma unroll
      for (int i = 0; i < 4; ++i)
        #pragma unroll
        for (int j = 0; j < 4; ++j)
          acc[i][j] = fmaf(av[i], wv[j], acc[i][j]);
    }
    __syncthreads();
  }
  #pragma unroll
  for (int i = 0; i < 4; ++i) {
    int r = bm + (ty << 2) + i;
    if (r >= M) continue;
    #pragma unroll
    for (int j = 0; j < 4; ++j) {
      int cidx = bn + (tx << 2) + j;
      if (cidx >= N) continue;
      out[(size_t)r * N + cidx] = acc[i][j] + bias[cidx];
    }
  }
}

// ---------------- host launch ----------------
extern "C" void kernel_launch(void* const* d_in, const int* in_sizes, int n_in,
                              void* d_out, int out_size, void* d_ws, size_t ws_size,
                              hipStream_t stream) {
  const float* x        = (const float*)d_in[0];
  const float* patch_w  = (const float*)d_in[1];
  const float* patch_b  = (const float*)d_in[2];
  const float* cls_tok  = (const float*)d_in[3];
  const float* pos      = (const float*)d_in[4];
  const float* ln1_g    = (const float*)d_in[5];
  const float* ln1_b    = (const float*)d_in[6];
  const float* qkv_w    = (const float*)d_in[7];
  const float* qkv_b    = (const float*)d_in[8];
  const float* proj_w   = (const float*)d_in[9];
  const float* proj_b   = (const float*)d_in[10];
  const float* ln2_g    = (const float*)d_in[11];
  const float* ln2_b    = (const float*)d_in[12];
  const float* fc1_w    = (const float*)d_in[13];
  const float* fc1_b    = (const float*)d_in[14];
  const float* fc2_w    = (const float*)d_in[15];
  const float* fc2_b    = (const float*)d_in[16];
  const float* norm_g   = (const float*)d_in[17];
  const float* norm_b   = (const float*)d_in[18];
  const float* head_w   = (const float*)d_in[19];
  const float* head_b   = (const float*)d_in[20];
  float* out = (float*)d_out;

  float* ws = (float*)d_ws;
  // ---- workspace layout (float offsets) ----
  float* hA       = ws;                          // [B,197,C] f32
  float* big      = ws + 4841472;                // qkv bf16 / fc1 hidden bf16 / im2col / patchout
  ushortT* big_u  = (ushortT*)big;
  float* patchout = big + 4816896;               // f32, patch-embed only
  float* hB       = ws + 14524416;               // [B,<=197,C] f32 ping-pong
  ushortT* lnb_u  = (ushortT*)(ws + 19365888);
  ushortT* attn_u = (ushortT*)(ws + 21786624);
  ushortT* wbuf_u = (ushortT*)(ws + 24207360);
  float* cls_attn = ws + 25092096;
  int*   idxbuf   = (int*)(ws + 25179904);
  float* cls0     = ws + 25191168;

  ushortT* wq = wbuf_u;
  ushortT* wp = wbuf_u + 442368;
  ushortT* w1 = wbuf_u + 589824;
  ushortT* w2 = wbuf_u + 1179648;

  // ---- patch embed ----
  {
    int total = BATCH * NPATCH * 768;
    im2col_bf16<<<(total + 255) / 256, 256, 0, stream>>>(x, big_u);
    wtrans_one<<<288, 256, 0, stream>>>(patch_w, wbuf_u, 768, CDIM);
    gemm_mfma<0, 0, 0><<<dim3(3, 98), 256, 0, stream>>>(big_u, wbuf_u, patch_b, nullptr, patchout,
                                                        BATCH * NPATCH, CDIM, 768);
    int tot2 = BATCH * NTOK0 * CDIM;
    assemble_kernel<<<(tot2 + 255) / 256, 256, 0, stream>>>(patchout, cls_tok, pos, hA);
  }

  float* h = hA;
  float* hOther = hB;
  int ncur = NTOK0;
  for (int i = 0; i < NLAYERS; ++i) {
    int M = BATCH * ncur;
    int gy = (M + 127) / 128;
    wtrans_layer<<<1728, 256, 0, stream>>>(qkv_w + (size_t)i * CDIM * 3 * CDIM,
                                           proj_w + (size_t)i * CDIM * CDIM,
                                           fc1_w + (size_t)i * CDIM * MLPD,
                                           fc2_w + (size_t)i * MLPD * CDIM,
                                           wq, wp, w1, w2);
    ln_bf16<<<(M + 3) / 4, 256, 0, stream>>>(h, lnb_u, ln1_g + i * CDIM, ln1_b + i * CDIM, M);
    gemm_mfma<0, 0, 1><<<dim3(9, gy), 256, 0, stream>>>(lnb_u, wq, qkv_b + i * 3 * CDIM, nullptr,
                                                        big_u, M, 3 * CDIM, CDIM);
    // attention (MFMA)
    {
      dim3 g((ncur + 63) / 64, NHEADS, BATCH);
      int ks = (ncur + 31) / 32;
      if (ks == 7)      attn3<7><<<g, 256, 0, stream>>>(big_u, attn_u, cls_attn, ncur);
      else if (ks == 6) attn3<6><<<g, 256, 0, stream>>>(big_u, attn_u, cls_attn, ncur);
      else if (ks == 5) attn3<5><<<g, 256, 0, stream>>>(big_u, attn_u, cls_attn, ncur);
      else              attn3<4><<<g, 256, 0, stream>>>(big_u, attn_u, cls_attn, ncur);
    }
    gemm_mfma<0, 1, 0><<<dim3(3, gy), 256, 0, stream>>>(attn_u, wp, proj_b + i * CDIM, h,
                                                        h, M, CDIM, CDIM);
    if (i == 2 || i == 4 || i == 6) {
      int keep = (i == 2) ? 176 : (i == 4) ? 149 : 119;
      int Nm1 = ncur - 1;
      topk_rank<<<BATCH, 256, 0, stream>>>(cls_attn, idxbuf, Nm1, keep);
      int newN = 1 + keep;
      size_t gtot = (size_t)BATCH * newN * CDIM;
      gather_kernel<<<(int)((gtot + 255) / 256), 256, 0, stream>>>(h, idxbuf, hOther, ncur, keep);
      float* tmp = h; h = hOther; hOther = tmp;
      ncur = newN;
      M = BATCH * ncur;
      gy = (M + 127) / 128;
    }
    ln_bf16<<<(M + 3) / 4, 256, 0, stream>>>(h, lnb_u, ln2_g + i * CDIM, ln2_b + i * CDIM, M);
    gemm_mfma<1, 0, 1><<<dim3(12, gy), 256, 0, stream>>>(lnb_u, w1, fc1_b + i * MLPD, nullptr,
                                                         big_u, M, MLPD, CDIM);
    gemm_mfma<0, 1, 0><<<dim3(3, gy), 256, 0, stream>>>(big_u, w2, fc2_b + i * CDIM, h,
                                                        h, M, CDIM, MLPD);
  }

  ln_kernel<<<BATCH, 64, 0, stream>>>(h, cls0, norm_g, norm_b, BATCH, (size_t)ncur * CDIM, CDIM);
  gemm_f32<<<dim3(2, 1), 256, 0, stream>>>(cls0, head_w, head_b, out, BATCH, NCLS, CDIM);
}

// Round 8
// 2451.278 us; speedup vs baseline: 5.8050x; 1.1221x over previous
//
#include <hip/hip_runtime.h>
#include <hip/hip_bf16.h>
#include <math.h>

// ---------------- model constants ----------------
#define BATCH 64
#define CDIM 384
#define NHEADS 6
#define HD 64
#define MLPD 1536
#define NLAYERS 12
#define NPATCH 196
#define NTOK0 197
#define NCLS 100

typedef unsigned short ushortT;
typedef __attribute__((ext_vector_type(8))) short short8v;
typedef __attribute__((ext_vector_type(4))) float float4v;

// ---------------- bf16 helpers ----------------
__device__ inline ushortT f2b(float f) {
  union { float f; unsigned u; } x; x.f = f;
  unsigned r = x.u + 0x7fffu + ((x.u >> 16) & 1u);
  return (ushortT)(r >> 16);
}
__device__ inline float b2f(ushortT u) {
  union { unsigned u; float f; } x; x.u = ((unsigned)u) << 16;
  return x.f;
}

// async global->LDS, 16B per lane; lds base must be wave-uniform (HW: base + lane*16)
__device__ inline void gload_lds16(const ushortT* g, ushortT* l) {
  __builtin_amdgcn_global_load_lds((const __attribute__((address_space(1))) void*)g,
                                   (__attribute__((address_space(3))) void*)l, 16, 0, 0);
}

// ---------------- wave helpers ----------------
__device__ inline float wave_sum(float v) {
  #pragma unroll
  for (int o = 32; o > 0; o >>= 1) v += __shfl_xor(v, o);
  return v;
}

// ---------------- im2col: x[B,3,224,224] -> P[B*196, 768] bf16 ----------------
__global__ __launch_bounds__(256) void im2col_bf16(const float* __restrict__ x, ushortT* __restrict__ P) {
  int i = blockIdx.x * 256 + threadIdx.x;
  const int total = BATCH * NPATCH * 768;
  if (i >= total) return;
  int k = i % 768;
  int row = i / 768;
  int c = k >> 8;
  int r = k & 255;
  int py = r >> 4, px = r & 15;
  int b = row / NPATCH;
  int p = row % NPATCH;
  int gy = p / 14, gx = p % 14;
  P[i] = f2b(x[(((size_t)b * 3 + c) * 224 + gy * 16 + py) * 224 + gx * 16 + px]);
}

// ---------------- assemble ----------------
__global__ __launch_bounds__(256) void assemble_kernel(const float* __restrict__ patchout,
                                                       const float* __restrict__ cls_tok,
                                                       const float* __restrict__ pos,
                                                       float* __restrict__ h) {
  int i = blockIdx.x * 256 + threadIdx.x;
  const int total = BATCH * NTOK0 * CDIM;
  if (i >= total) return;
  int c = i % CDIM;
  int n = (i / CDIM) % NTOK0;
  int b = i / (CDIM * NTOK0);
  float v = (n == 0) ? cls_tok[c] : patchout[((size_t)b * NPATCH + (n - 1)) * CDIM + c];
  h[i] = v + pos[n * CDIM + c];
}

// ---------------- weight transpose + bf16 convert ----------------
__global__ __launch_bounds__(256) void wtrans_layer(const float* __restrict__ qkv_w, const float* __restrict__ proj_w,
                                                    const float* __restrict__ fc1_w, const float* __restrict__ fc2_w,
                                                    ushortT* __restrict__ wq, ushortT* __restrict__ wp,
                                                    ushortT* __restrict__ w1, ushortT* __restrict__ w2) {
  int id = blockIdx.x;
  const float* W; ushortT* O; int K, N, t;
  if (id < 432)       { W = qkv_w; O = wq; K = 384;  N = 1152; t = id; }
  else if (id < 576)  { W = proj_w; O = wp; K = 384; N = 384;  t = id - 432; }
  else if (id < 1152) { W = fc1_w; O = w1; K = 384;  N = 1536; t = id - 576; }
  else                { W = fc2_w; O = w2; K = 1536; N = 384;  t = id - 1152; }
  int tilesK = K >> 5;
  int k0 = (t % tilesK) << 5, n0 = (t / tilesK) << 5;
  __shared__ float tile[32][33];
  int tx = threadIdx.x & 31, ty = threadIdx.x >> 5;
  #pragma unroll
  for (int i = 0; i < 4; ++i)
    tile[ty + 8 * i][tx] = W[(size_t)(k0 + ty + 8 * i) * N + n0 + tx];
  __syncthreads();
  #pragma unroll
  for (int i = 0; i < 4; ++i)
    O[(size_t)(n0 + ty + 8 * i) * K + k0 + tx] = f2b(tile[tx][ty + 8 * i]);
}

// single matrix version (patch embed weights)
__global__ __launch_bounds__(256) void wtrans_one(const float* __restrict__ W, ushortT* __restrict__ O, int K, int N) {
  int t = blockIdx.x;
  int tilesK = K >> 5;
  int k0 = (t % tilesK) << 5, n0 = (t / tilesK) << 5;
  __shared__ float tile[32][33];
  int tx = threadIdx.x & 31, ty = threadIdx.x >> 5;
  #pragma unroll
  for (int i = 0; i < 4; ++i)
    tile[ty + 8 * i][tx] = W[(size_t)(k0 + ty + 8 * i) * N + n0 + tx];
  __syncthreads();
  #pragma unroll
  for (int i = 0; i < 4; ++i)
    O[(size_t)(n0 + ty + 8 * i) * K + k0 + tx] = f2b(tile[tx][ty + 8 * i]);
}

// ---------------- MFMA bf16 GEMM: 2-phase double-buffered, XCD-swizzled ----------------
// out = act(A@Wt^T + bias) [+ res]; A:[M][K] bf16, Wt:[N][K] bf16. N%128==0.
// 1D grid of gx*gy blocks; bijective XCD chunk swizzle (m204) for A-panel L2 locality.
template<int ACT, int RES, int OBF>
__global__ __launch_bounds__(256) void gemm_mfma(const ushortT* __restrict__ A, const ushortT* __restrict__ Wt,
                                                 const float* __restrict__ bias, const float* __restrict__ res,
                                                 void* __restrict__ outp, int M, int N, int K, int gx) {
  __shared__ __align__(16) ushortT Asl[2][4096];  // [128][32] linear per buffer
  __shared__ __align__(16) ushortT Bsl[2][4096];
  const int tid = threadIdx.x;
  const int lane = tid & 63, wave = tid >> 6;
  const int wr = wave >> 1, wc = wave & 1;

  // bijective XCD swizzle: consecutive wgid (same A-panel) -> same XCD chunk
  const int nwg = gridDim.x;
  const int orig = blockIdx.x;
  const int q = nwg >> 3, r = nwg & 7;
  const int xcd = orig & 7;
  const int wgid = (xcd < r ? xcd * (q + 1) : r * (q + 1) + (xcd - r) * q) + (orig >> 3);
  const int bm = (wgid / gx) * 128, bn = (wgid % gx) * 128;

  float4v acc[4][4] = {};

  // staging map: LDS elem off = j*2048 + wave*512 + lane*8
  //   -> row = j*64 + wave*16 + lane/4, col = (lane&3)*8
  const int srow = wave * 16 + (lane >> 2);
  const int scol = (lane & 3) * 8;
  const ushortT* ag0 = A + (size_t)(bm + srow) * K + scol;
  const ushortT* ag1 = A + (size_t)(bm + 64 + srow) * K + scol;
  const ushortT* bg0 = Wt + (size_t)(bn + srow) * K + scol;
  const ushortT* bg1 = Wt + (size_t)(bn + 64 + srow) * K + scol;

  const int fr = lane & 15, g8 = (lane >> 4) * 8;
  const int nt = K >> 5;

  // prologue: stage tile 0
  gload_lds16(ag0, &Asl[0][wave * 512]);
  gload_lds16(ag1, &Asl[0][2048 + wave * 512]);
  gload_lds16(bg0, &Bsl[0][wave * 512]);
  gload_lds16(bg1, &Bsl[0][2048 + wave * 512]);
  __syncthreads();

  int cur = 0;
  for (int t = 0; t < nt; ++t) {
    // issue next-tile prefetch FIRST (flies under ds_read+MFMA below)
    if (t + 1 < nt) {
      const int k0 = (t + 1) << 5;
      const int nxt = cur ^ 1;
      gload_lds16(ag0 + k0, &Asl[nxt][wave * 512]);
      gload_lds16(ag1 + k0, &Asl[nxt][2048 + wave * 512]);
      gload_lds16(bg0 + k0, &Bsl[nxt][wave * 512]);
      gload_lds16(bg1 + k0, &Bsl[nxt][2048 + wave * 512]);
    }
    short8v af[4], bf[4];
    #pragma unroll
    for (int i = 0; i < 4; ++i) {
      af[i] = *(const short8v*)&Asl[cur][(wr * 64 + i * 16 + fr) * 32 + g8];
      bf[i] = *(const short8v*)&Bsl[cur][(wc * 64 + i * 16 + fr) * 32 + g8];
    }
    #pragma unroll
    for (int i = 0; i < 4; ++i)
      #pragma unroll
      for (int j = 0; j < 4; ++j)
        acc[i][j] = __builtin_amdgcn_mfma_f32_16x16x32_bf16(af[i], bf[j], acc[i][j], 0, 0, 0);
    if (t + 1 < nt) {
      __syncthreads();  // drains vmcnt -> next buffer ready; also fences buf reuse
      cur ^= 1;
    }
  }

  const int c0 = lane & 15;
  const int r4 = (lane >> 4) * 4;
  #pragma unroll
  for (int i = 0; i < 4; ++i) {
    #pragma unroll
    for (int j = 0; j < 4; ++j) {
      const int col = bn + wc * 64 + j * 16 + c0;
      #pragma unroll
      for (int qq = 0; qq < 4; ++qq) {
        const int row = bm + wr * 64 + i * 16 + r4 + qq;
        if (row < M) {
          float v = acc[i][j][qq] + bias[col];
          if (ACT == 1) v = 0.5f * v * (1.0f + erff(v * 0.70710678118654752f));
          if (RES) v += res[(size_t)row * N + col];
          if (OBF) ((ushortT*)outp)[(size_t)row * N + col] = f2b(v);
          else     ((float*)outp)[(size_t)row * N + col] = v;
        }
      }
    }
  }
}

// ---------------- layernorm f32 -> bf16 (4 rows per 256-thread block) ----------------
__global__ __launch_bounds__(256) void ln_bf16(const float* __restrict__ in, ushortT* __restrict__ out,
                                               const float* __restrict__ g, const float* __restrict__ bb,
                                               int rows) {
  const int r = blockIdx.x * 4 + (threadIdx.x >> 6);
  if (r >= rows) return;
  const int t = threadIdx.x & 63;
  const float* xr = in + (size_t)r * CDIM;
  ushortT* orow = out + (size_t)r * CDIM;
  float v[6];
  float s = 0.f;
  #pragma unroll
  for (int i = 0; i < 6; ++i) { v[i] = xr[i * 64 + t]; s += v[i]; }
  s = wave_sum(s);
  float mean = s * (1.0f / CDIM);
  float q = 0.f;
  #pragma unroll
  for (int i = 0; i < 6; ++i) { float d = v[i] - mean; q += d * d; }
  q = wave_sum(q);
  float rstd = rsqrtf(q * (1.0f / CDIM) + 1e-6f);
  #pragma unroll
  for (int i = 0; i < 6; ++i) {
    int c = i * 64 + t;
    orow[c] = f2b((v[i] - mean) * rstd * g[c] + bb[c]);
  }
}

// ---------------- layernorm f32->f32 ----------------
__global__ __launch_bounds__(64) void ln_kernel(const float* __restrict__ in, float* __restrict__ out,
                                                const float* __restrict__ g, const float* __restrict__ bb,
                                                int rows, size_t in_stride, size_t out_stride) {
  int r = blockIdx.x;
  if (r >= rows) return;
  const float* xr = in + (size_t)r * in_stride;
  float* orow = out + (size_t)r * out_stride;
  int t = threadIdx.x;
  float v[6];
  float s = 0.f;
  #pragma unroll
  for (int i = 0; i < 6; ++i) { v[i] = xr[i * 64 + t]; s += v[i]; }
  s = wave_sum(s);
  float mean = s * (1.0f / CDIM);
  float q = 0.f;
  #pragma unroll
  for (int i = 0; i < 6; ++i) { float d = v[i] - mean; q += d * d; }
  q = wave_sum(q);
  float rstd = rsqrtf(q * (1.0f / CDIM) + 1e-6f);
  #pragma unroll
  for (int i = 0; i < 6; ++i) {
    int c = i * 64 + t;
    orow[c] = (v[i] - mean) * rstd * g[c] + bb[c];
  }
}

// ---------------- attention v3: MFMA ----------------
template<int KS>
__global__ __launch_bounds__(256) void attn3(const ushortT* __restrict__ qkv, ushortT* __restrict__ attnout,
                                             float* __restrict__ cls_attn, int N) {
  constexpr int NT = 2 * KS;
  constexpr int KT = 32 * KS;
  const int h = blockIdx.y, b = blockIdx.z;
  const int rb = blockIdx.x * 64;
  const int tid = threadIdx.x;
  const int w = tid >> 6, l = tid & 63;
  const int c = l & 15, g = l >> 4;

  __shared__ __align__(16) ushortT Vt[64][232];      // V^T: [dim][token]
  __shared__ __align__(16) ushortT Ps[4][16][232];   // per-wave P (bf16)

  const ushortT* bq = qkv + (size_t)(b * N) * 1152 + (size_t)h * 64;

  // ---- stage V transposed ----
  {
    const int vr = tid >> 3, vc = (tid & 7) * 8;
    for (int p = 0; p < KT; p += 32) {
      const int m = vr + p;
      if (m < N) {
        short8v v8 = *(const short8v*)(bq + (size_t)m * 1152 + 768 + vc);
        #pragma unroll
        for (int j = 0; j < 8; ++j) Vt[vc + j][m] = (ushortT)v8[j];
      } else if (m < KT) {
        #pragma unroll
        for (int j = 0; j < 8; ++j) Vt[vc + j][m] = 0;
      }
    }
  }
  __syncthreads();

  // ---- Q A-fragments from global ----
  short8v qf0, qf1;
  {
    int row = rb + 16 * w + c; if (row >= N) row = N - 1;
    const ushortT* qrow = bq + (size_t)row * 1152;
    qf0 = *(const short8v*)(qrow + g * 8);
    qf1 = *(const short8v*)(qrow + 32 + g * 8);
  }

  // ---- S = Q@K^T ----
  float4v sc[NT];
  #pragma unroll
  for (int kt = 0; kt < NT; ++kt) {
    int krow = 16 * kt + c; if (krow >= N) krow = N - 1;
    const ushortT* kr = bq + (size_t)krow * 1152 + 384;
    short8v b0 = *(const short8v*)(kr + g * 8);
    short8v b1 = *(const short8v*)(kr + 32 + g * 8);
    float4v a = {};
    a = __builtin_amdgcn_mfma_f32_16x16x32_bf16(qf0, b0, a, 0, 0, 0);
    a = __builtin_amdgcn_mfma_f32_16x16x32_bf16(qf1, b1, a, 0, 0, 0);
    sc[kt] = a;
  }

  // ---- softmax ----
  float m4[4] = {-INFINITY, -INFINITY, -INFINITY, -INFINITY};
  #pragma unroll
  for (int kt = 0; kt < NT; ++kt) {
    const bool valid = (16 * kt + c) < N;
    #pragma unroll
    for (int q = 0; q < 4; ++q) {
      float s = valid ? sc[kt][q] * 0.125f : -INFINITY;
      sc[kt][q] = s;
      m4[q] = fmaxf(m4[q], s);
    }
  }
  #pragma unroll
  for (int q = 0; q < 4; ++q) {
    #pragma unroll
    for (int o = 1; o <= 8; o <<= 1) m4[q] = fmaxf(m4[q], __shfl_xor(m4[q], o));
  }
  float sum4[4] = {0.f, 0.f, 0.f, 0.f};
  #pragma unroll
  for (int kt = 0; kt < NT; ++kt) {
    #pragma unroll
    for (int q = 0; q < 4; ++q) {
      float e = __expf(sc[kt][q] - m4[q]);
      sc[kt][q] = e;
      sum4[q] += e;
    }
  }
  #pragma unroll
  for (int q = 0; q < 4; ++q) {
    #pragma unroll
    for (int o = 1; o <= 8; o <<= 1) sum4[q] += __shfl_xor(sum4[q], o);
  }
  float inv4[4];
  #pragma unroll
  for (int q = 0; q < 4; ++q) inv4[q] = 1.0f / sum4[q];

  // ---- write P ----
  #pragma unroll
  for (int kt = 0; kt < NT; ++kt) {
    #pragma unroll
    for (int q = 0; q < 4; ++q) Ps[w][4 * g + q][16 * kt + c] = f2b(sc[kt][q]);
  }

  // ---- CLS attention probs ----
  if (rb == 0 && w == 0 && g == 0) {
    const float inv0 = inv4[0];
    #pragma unroll
    for (int kt = 0; kt < NT; ++kt) {
      const int col = 16 * kt + c;
      if (col >= 1 && col < N)
        cls_attn[((size_t)b * NHEADS + h) * (N - 1) + (col - 1)] = sc[kt][0] * inv0;
    }
  }

  // ---- O = P @ V ----
  float4v oacc[4] = {};
  #pragma unroll
  for (int s2 = 0; s2 < KS; ++s2) {
    short8v pa = *(const short8v*)&Ps[w][c][32 * s2 + 8 * g];
    #pragma unroll
    for (int nt = 0; nt < 4; ++nt) {
      short8v vb = *(const short8v*)&Vt[16 * nt + c][32 * s2 + 8 * g];
      oacc[nt] = __builtin_amdgcn_mfma_f32_16x16x32_bf16(pa, vb, oacc[nt], 0, 0, 0);
    }
  }

  // ---- epilogue ----
  #pragma unroll
  for (int nt = 0; nt < 4; ++nt) {
    #pragma unroll
    for (int q = 0; q < 4; ++q) {
      const int row = rb + 16 * w + 4 * g + q;
      if (row < N)
        attnout[((size_t)(b * N + row)) * CDIM + h * 64 + 16 * nt + c] = f2b(oacc[nt][q] * inv4[q]);
    }
  }
}

// ---------------- fused clsscore + rank top-k ----------------
__global__ __launch_bounds__(256) void topk_rank(const float* __restrict__ cls_attn, int* __restrict__ idx,
                                                 int Nm1, int Kkeep) {
  const int b = blockIdx.x;
  const int t = threadIdx.x;
  __shared__ float s_sc[224];
  if (t < Nm1) {
    const float* ca = cls_attn + (size_t)b * NHEADS * Nm1 + t;
    float s = 0.f;
    #pragma unroll
    for (int h = 0; h < NHEADS; ++h) s += ca[h * Nm1];
    s_sc[t] = s * (1.0f / NHEADS);
  }
  __syncthreads();
  if (t < Nm1) {
    const float mys = s_sc[t];
    int r = 0;
    for (int i = 0; i < Nm1; ++i) {
      float si = s_sc[i];
      r += (si > mys || (si == mys && i < t)) ? 1 : 0;
    }
    if (r < Kkeep) idx[b * Kkeep + r] = t;
  }
}

// ---------------- gather pruned tokens ----------------
__global__ __launch_bounds__(256) void gather_kernel(const float* __restrict__ h, const int* __restrict__ idx,
                                                     float* __restrict__ outb, int N, int Kkeep) {
  size_t total = (size_t)BATCH * (1 + Kkeep) * CDIM;
  size_t i = (size_t)blockIdx.x * 256 + threadIdx.x;
  if (i >= total) return;
  int c = (int)(i % CDIM);
  size_t r = i / CDIM;
  int n = (int)(r % (1 + Kkeep));
  int b = (int)(r / (1 + Kkeep));
  int src = (n == 0) ? 0 : 1 + idx[b * Kkeep + (n - 1)];
  outb[i] = h[((size_t)b * N + src) * CDIM + c];
}

// ---------------- small f32 GEMM (head only) ----------------
__global__ __launch_bounds__(256) void gemm_f32(const float* __restrict__ A, const float* __restrict__ W,
                                                const float* __restrict__ bias, float* __restrict__ out,
                                                int M, int N, int K) {
  __shared__ __align__(16) float As[16][64];
  __shared__ __align__(16) float Ws[16][64];
  const int tid = threadIdx.x;
  const int tx = tid & 15, ty = tid >> 4;
  const int bm = blockIdx.y * 64, bn = blockIdx.x * 64;
  float acc[4][4] = {};
  const int ma = tid >> 2;
  const int ka = (tid & 3) << 2;
  const int kw = ty;
  const int nw = tx << 2;
  for (int k0 = 0; k0 < K; k0 += 16) {
    {
      float4 a4 = make_float4(0.f, 0.f, 0.f, 0.f);
      if (bm + ma < M) a4 = *reinterpret_cast<const float4*>(&A[(size_t)(bm + ma) * K + k0 + ka]);
      As[ka + 0][ma] = a4.x; As[ka + 1][ma] = a4.y; As[ka + 2][ma] = a4.z; As[ka + 3][ma] = a4.w;
    }
    {
      const int gn = bn + nw;
      const float* wp = &W[(size_t)(k0 + kw) * N + gn];
      #pragma unroll
      for (int j = 0; j < 4; ++j) Ws[kw][nw + j] = (gn + j < N) ? wp[j] : 0.f;
    }
    __syncthreads();
    #pragma unroll
    for (int kk = 0; kk < 16; ++kk) {
      float4 a = *reinterpret_cast<const float4*>(&As[kk][ty << 2]);
      float4 w = *reinterpret_cast<const float4*>(&Ws[kk][tx << 2]);
      float av[4] = {a.x, a.y, a.z, a.w};
      float wv[4] = {w.x, w.y, w.z, w.w};
      #pragma unroll
      for (int i = 0; i < 4; ++i)
        #pragma unroll
        for (int j = 0; j < 4; ++j)
          acc[i][j] = fmaf(av[i], wv[j], acc[i][j]);
    }
    __syncthreads();
  }
  #pragma unroll
  for (int i = 0; i < 4; ++i) {
    int r = bm + (ty << 2) + i;
    if (r >= M) continue;
    #pragma unroll
    for (int j = 0; j < 4; ++j) {
      int cidx = bn + (tx << 2) + j;
      if (cidx >= N) continue;
      out[(size_t)r * N + cidx] = acc[i][j] + bias[cidx];
    }
  }
}

// ---------------- host launch ----------------
extern "C" void kernel_launch(void* const* d_in, const int* in_sizes, int n_in,
                              void* d_out, int out_size, void* d_ws, size_t ws_size,
                              hipStream_t stream) {
  const float* x        = (const float*)d_in[0];
  const float* patch_w  = (const float*)d_in[1];
  const float* patch_b  = (const float*)d_in[2];
  const float* cls_tok  = (const float*)d_in[3];
  const float* pos      = (const float*)d_in[4];
  const float* ln1_g    = (const float*)d_in[5];
  const float* ln1_b    = (const float*)d_in[6];
  const float* qkv_w    = (const float*)d_in[7];
  const float* qkv_b    = (const float*)d_in[8];
  const float* proj_w   = (const float*)d_in[9];
  const float* proj_b   = (const float*)d_in[10];
  const float* ln2_g    = (const float*)d_in[11];
  const float* ln2_b    = (const float*)d_in[12];
  const float* fc1_w    = (const float*)d_in[13];
  const float* fc1_b    = (const float*)d_in[14];
  const float* fc2_w    = (const float*)d_in[15];
  const float* fc2_b    = (const float*)d_in[16];
  const float* norm_g   = (const float*)d_in[17];
  const float* norm_b   = (const float*)d_in[18];
  const float* head_w   = (const float*)d_in[19];
  const float* head_b   = (const float*)d_in[20];
  float* out = (float*)d_out;

  float* ws = (float*)d_ws;
  // ---- workspace layout (float offsets) ----
  float* hA       = ws;                          // [B,197,C] f32
  float* big      = ws + 4841472;                // qkv bf16 / fc1 hidden bf16 / im2col / patchout
  ushortT* big_u  = (ushortT*)big;
  float* patchout = big + 4816896;               // f32, patch-embed only
  float* hB       = ws + 14524416;               // [B,<=197,C] f32 ping-pong
  ushortT* lnb_u  = (ushortT*)(ws + 19365888);
  ushortT* attn_u = (ushortT*)(ws + 21786624);
  ushortT* wbuf_u = (ushortT*)(ws + 24207360);
  float* cls_attn = ws + 25092096;
  int*   idxbuf   = (int*)(ws + 25179904);
  float* cls0     = ws + 25191168;

  ushortT* wq = wbuf_u;
  ushortT* wp = wbuf_u + 442368;
  ushortT* w1 = wbuf_u + 589824;
  ushortT* w2 = wbuf_u + 1179648;

  // ---- patch embed ----
  {
    int total = BATCH * NPATCH * 768;
    im2col_bf16<<<(total + 255) / 256, 256, 0, stream>>>(x, big_u);
    wtrans_one<<<288, 256, 0, stream>>>(patch_w, wbuf_u, 768, CDIM);
    gemm_mfma<0, 0, 0><<<3 * 98, 256, 0, stream>>>(big_u, wbuf_u, patch_b, nullptr, patchout,
                                                   BATCH * NPATCH, CDIM, 768, 3);
    int tot2 = BATCH * NTOK0 * CDIM;
    assemble_kernel<<<(tot2 + 255) / 256, 256, 0, stream>>>(patchout, cls_tok, pos, hA);
  }

  float* h = hA;
  float* hOther = hB;
  int ncur = NTOK0;
  for (int i = 0; i < NLAYERS; ++i) {
    int M = BATCH * ncur;
    int gy = (M + 127) / 128;
    wtrans_layer<<<1728, 256, 0, stream>>>(qkv_w + (size_t)i * CDIM * 3 * CDIM,
                                           proj_w + (size_t)i * CDIM * CDIM,
                                           fc1_w + (size_t)i * CDIM * MLPD,
                                           fc2_w + (size_t)i * MLPD * CDIM,
                                           wq, wp, w1, w2);
    ln_bf16<<<(M + 3) / 4, 256, 0, stream>>>(h, lnb_u, ln1_g + i * CDIM, ln1_b + i * CDIM, M);
    gemm_mfma<0, 0, 1><<<9 * gy, 256, 0, stream>>>(lnb_u, wq, qkv_b + i * 3 * CDIM, nullptr,
                                                   big_u, M, 3 * CDIM, CDIM, 9);
    // attention (MFMA)
    {
      dim3 g((ncur + 63) / 64, NHEADS, BATCH);
      int ks = (ncur + 31) / 32;
      if (ks == 7)      attn3<7><<<g, 256, 0, stream>>>(big_u, attn_u, cls_attn, ncur);
      else if (ks == 6) attn3<6><<<g, 256, 0, stream>>>(big_u, attn_u, cls_attn, ncur);
      else if (ks == 5) attn3<5><<<g, 256, 0, stream>>>(big_u, attn_u, cls_attn, ncur);
      else              attn3<4><<<g, 256, 0, stream>>>(big_u, attn_u, cls_attn, ncur);
    }
    gemm_mfma<0, 1, 0><<<3 * gy, 256, 0, stream>>>(attn_u, wp, proj_b + i * CDIM, h,
                                                   h, M, CDIM, CDIM, 3);
    if (i == 2 || i == 4 || i == 6) {
      int keep = (i == 2) ? 176 : (i == 4) ? 149 : 119;
      int Nm1 = ncur - 1;
      topk_rank<<<BATCH, 256, 0, stream>>>(cls_attn, idxbuf, Nm1, keep);
      int newN = 1 + keep;
      size_t gtot = (size_t)BATCH * newN * CDIM;
      gather_kernel<<<(int)((gtot + 255) / 256), 256, 0, stream>>>(h, idxbuf, hOther, ncur, keep);
      float* tmp = h; h = hOther; hOther = tmp;
      ncur = newN;
      M = BATCH * ncur;
      gy = (M + 127) / 128;
    }
    ln_bf16<<<(M + 3) / 4, 256, 0, stream>>>(h, lnb_u, ln2_g + i * CDIM, ln2_b + i * CDIM, M);
    gemm_mfma<1, 0, 1><<<12 * gy, 256, 0, stream>>>(lnb_u, w1, fc1_b + i * MLPD, nullptr,
                                                    big_u, M, MLPD, CDIM, 12);
    gemm_mfma<0, 1, 0><<<3 * gy, 256, 0, stream>>>(big_u, w2, fc2_b + i * CDIM, h,
                                                   h, M, CDIM, MLPD, 3);
  }

  ln_kernel<<<BATCH, 64, 0, stream>>>(h, cls0, norm_g, norm_b, BATCH, (size_t)ncur * CDIM, CDIM);
  gemm_f32<<<dim3(2, 1), 256, 0, stream>>>(cls0, head_w, head_b, out, BATCH, NCLS, CDIM);
}